// Round 4
// baseline (452.541 us; speedup 1.0000x reference)
//
#include <hip/hip_runtime.h>
#include <hip/hip_bf16.h>

constexpr int NB = 32;      // batch
constexpr int NA = 16320;   // anchors
constexpr int NG = 32;      // gt boxes per image
constexpr int NC = 81;      // ODM classes
constexpr int ODM_TILE = 64;               // anchors per block in k_odm_loss
constexpr int ODM_TILE_F = ODM_TILE * NC;  // 5184 floats = 20736 B

__device__ __forceinline__ float sl1(float d) {
    float ad = fabsf(d);
    return ad < 1.f ? 0.5f * d * d : ad - 0.5f;
}

// ---------------- K0: decode anchors to point-form + area -------------------------------
// row 0 = base anchors (ARM), rows 1..NB = per-image refined anchors (ODM)
__global__ __launch_bounds__(256) void k_decode(
    const float* __restrict__ anchors,     // [NA*4] cxcywh
    const float* __restrict__ refine_loc,  // [NB*NA*4]
    float4* __restrict__ pf,               // [(NB+1)*NA] xyxy
    float* __restrict__ parea)             // [(NB+1)*NA]
{
    int idx = blockIdx.x * 256 + threadIdx.x;
    if (idx >= (NB + 1) * NA) return;
    int row = idx / NA;
    int a = idx - row * NA;
    float4 an = *(const float4*)&anchors[(size_t)a * 4];
    float acx = an.x, acy = an.y, aw = an.z, ah = an.w;
    if (row > 0) {
        int b = row - 1;
        float4 rl = *(const float4*)&refine_loc[((size_t)b * NA + a) * 4];
        acx += rl.x * 0.1f * aw;
        acy += rl.y * 0.1f * ah;
        aw *= __expf(rl.z * 0.2f);
        ah *= __expf(rl.w * 0.2f);
    }
    float4 o;
    o.x = acx - aw * 0.5f; o.y = acy - ah * 0.5f;
    o.z = acx + aw * 0.5f; o.w = acy + ah * 0.5f;
    pf[idx] = o;
    parea[idx] = (o.z - o.x) * (o.w - o.y);
}

// ---------------- K1a: per-anchor best gt ----------------------------------------------
__global__ __launch_bounds__(256) void k_match_a(
    const float4* __restrict__ pf,
    const float* __restrict__ parea,
    const float* __restrict__ gt_boxes,    // [NB*NG*4] xyxy
    float* __restrict__ ws_ov,             // [2*NB*NA]
    unsigned char* __restrict__ ws_idx)    // [2*NB*NA]
{
    int row = blockIdx.x >> 6;             // 0..63 = lossId*32 + b
    int chunk = blockIdx.x & 63;
    int lossId = row >> 5, b = row & 31;
    int tid = threadIdx.x;
    __shared__ float4 s_gt[NG];
    __shared__ float s_ga[NG];
    if (tid < NG) {
        float4 g = *(const float4*)&gt_boxes[(size_t)(b * NG + tid) * 4];
        s_gt[tid] = g;
        s_ga[tid] = (g.z - g.x) * (g.w - g.y);
    }
    __syncthreads();
    int a = chunk * 256 + tid;
    if (a >= NA) return;
    int prow = lossId ? (1 + b) : 0;
    float4 A = pf[(size_t)prow * NA + a];
    float aarea = parea[(size_t)prow * NA + a];
    float best = -1.f; int bg = 0;
    #pragma unroll 4
    for (int g = 0; g < NG; g++) {
        float4 G = s_gt[g];
        float tlx = fmaxf(G.x, A.x);
        float tly = fmaxf(G.y, A.y);
        float brx = fminf(G.z, A.z);
        float bry = fminf(G.w, A.w);
        float w = brx - tlx; w = w > 0.f ? w : 0.f;
        float h = bry - tly; h = h > 0.f ? h : 0.f;
        float inter = w * h;
        float uni = s_ga[g] + aarea - inter;
        float ov = inter * __builtin_amdgcn_rcpf(uni);
        if (ov > best) { best = ov; bg = g; }   // strict > keeps first (smallest) g
    }
    size_t sec = (size_t)row * NA;
    ws_ov[sec + a] = best;
    ws_idx[sec + a] = (unsigned char)bg;
}

// ---------------- K1b: per-gt best anchor (loop-swapped, row read once) -----------------
// grid: 64 rows * 8 chunks; thread (g = tid&31, s = tid>>5) scans strided anchors for gt g
__global__ __launch_bounds__(256) void k_match_g(
    const float4* __restrict__ pf,
    const float* __restrict__ parea,
    const float* __restrict__ gt_boxes,
    unsigned long long* __restrict__ ws_best)  // [2*NB*NG], pre-zeroed
{
    int row = blockIdx.x >> 3;
    int chunk = blockIdx.x & 7;
    int lossId = row >> 5, b = row & 31;
    int tid = threadIdx.x;
    int g = tid & 31;
    int s = tid >> 5;                      // 0..7
    float4 G = *(const float4*)&gt_boxes[(size_t)(b * NG + g) * 4];
    float ga = (G.z - G.x) * (G.w - G.y);
    int prow = lossId ? (1 + b) : 0;
    const float4* P = pf + (size_t)prow * NA;
    const float* PA = parea + (size_t)prow * NA;
    const int CH = NA / 8;                 // 2040
    int a0 = chunk * CH;
    unsigned long long key = 0ull;
    for (int a = a0 + s; a < a0 + CH; a += 8) {
        float4 A = P[a];
        float aa = PA[a];
        float tlx = fmaxf(G.x, A.x), tly = fmaxf(G.y, A.y);
        float brx = fminf(G.z, A.z), bry = fminf(G.w, A.w);
        float w = brx - tlx; w = w > 0.f ? w : 0.f;
        float h = bry - tly; h = h > 0.f ? h : 0.f;
        float inter = w * h;
        float ov = inter * __builtin_amdgcn_rcpf(ga + aa - inter);
        unsigned long long k = ((unsigned long long)__float_as_uint(ov) << 32)
                               | (unsigned)(0xFFFFFFFFu - (unsigned)a);
        key = k > key ? k : key;
    }
    __shared__ unsigned long long s_best[NG];
    if (tid < NG) s_best[tid] = 0ull;
    __syncthreads();
    atomicMax(&s_best[g], key);
    __syncthreads();
    if (tid < NG && s_best[tid])
        atomicMax(&ws_best[(size_t)row * NG + tid], s_best[tid]);
}

// ---------------- K2: conf assignment with guarantee override + pos count ---------------
__global__ __launch_bounds__(256) void k_conf(
    const int* __restrict__ gt_labels,     // [NB*NG]
    const unsigned long long* __restrict__ ws_best,
    const float* __restrict__ ws_ov,
    const unsigned char* __restrict__ ws_idx,
    int* __restrict__ match,               // [2*NB*NA] packed conf | g<<16
    int* __restrict__ pos_num)             // [2*NB], pre-zeroed
{
    int row = blockIdx.x >> 3;             // 64 rows
    int chunk = blockIdx.x & 7;            // 8 chunks of 2040
    int lossId = row >> 5, b = row & 31;
    int tid = threadIdx.x;
    __shared__ int s_oa[NG];
    __shared__ int s_lab[NG];
    __shared__ unsigned s_mask[512];       // NA bits = 510 words
    for (int i = tid; i < 512; i += 256) s_mask[i] = 0u;
    __syncthreads();
    if (tid < NG) {
        s_lab[tid] = lossId ? gt_labels[b * NG + tid] : 0;
        unsigned a = 0xFFFFFFFFu - (unsigned)(ws_best[(size_t)row * NG + tid] & 0xFFFFFFFFull);
        s_oa[tid] = (int)a;
        atomicOr(&s_mask[a >> 5], 1u << (a & 31));
    }
    __syncthreads();
    size_t sec = (size_t)row * NA;
    int base = chunk * 2040;
    int cnt = 0;
    for (int a = base + tid; a < base + 2040; a += 256) {
        float ov = ws_ov[sec + a];
        int g = ws_idx[sec + a];
        if (s_mask[a >> 5] & (1u << (a & 31))) {
            for (int j = NG - 1; j >= 0; j--)      // last gt wins on duplicates
                if (s_oa[j] == a) { g = j; ov = 2.0f; break; }
        }
        int conf = (ov < 0.5f) ? 0 : (s_lab[g] + 1);
        match[sec + a] = conf | (g << 16);
        cnt += (conf > 0);
    }
    #pragma unroll
    for (int o = 32; o > 0; o >>= 1) cnt += __shfl_down(cnt, o);
    __shared__ int s_c[4];
    if ((tid & 63) == 0) s_c[tid >> 6] = cnt;
    __syncthreads();
    if (tid == 0) atomicAdd(&pos_num[row], s_c[0] + s_c[1] + s_c[2] + s_c[3]);
}

__device__ __forceinline__ void block_reduce2_atomic(float v0, float v1, float* a0, float* a1) {
    #pragma unroll
    for (int o = 32; o > 0; o >>= 1) { v0 += __shfl_down(v0, o); v1 += __shfl_down(v1, o); }
    __shared__ float s0[8], s1[8];
    int w = threadIdx.x >> 6;
    if ((threadIdx.x & 63) == 0) { s0[w] = v0; s1[w] = v1; }
    __syncthreads();
    if (threadIdx.x == 0) {
        float t0 = 0.f, t1 = 0.f;
        int nw = blockDim.x >> 6;
        for (int i = 0; i < nw; i++) { t0 += s0[i]; t1 += s1[i]; }
        atomicAdd(a0, t0); atomicAdd(a1, t1);
    }
}

// ---------------- K3a: ARM loss (C=2), thread per anchor --------------------------------
__global__ __launch_bounds__(256) void k_arm_loss(
    const float* __restrict__ objectness,  // [NB*NA*2]
    const float* __restrict__ refine_loc,  // pred_loc for ARM
    const float* __restrict__ anchors,
    const float* __restrict__ gt_boxes,
    const int* __restrict__ match,         // ARM section
    float* __restrict__ negce,             // ARM section
    float* __restrict__ acc)               // acc[0]=pos_ce, acc[1]=loc
{
    int idx = blockIdx.x * 256 + threadIdx.x;
    float pce = 0.f, ploc = 0.f;
    if (idx < NB * NA) {
        int b = idx / NA, a = idx - b * NA;
        float2 x = *(const float2*)&objectness[(size_t)idx * 2];
        float mx = fmaxf(x.x, x.y);
        float s = __expf(x.x - mx) + __expf(x.y - mx);
        float lse = mx + __logf(s);
        int m = match[idx]; int conf = m & 0xFFFF; int g = m >> 16;
        float ce = lse - (conf ? x.y : x.x);
        if (conf > 0) {
            pce = ce;
            negce[idx] = 0.f;
            float4 an = *(const float4*)&anchors[(size_t)a * 4];
            const float* gb = &gt_boxes[(size_t)(b * NG + g) * 4];
            float mcx = (gb[0] + gb[2]) * 0.5f, mcy = (gb[1] + gb[3]) * 0.5f;
            float mw = gb[2] - gb[0], mh = gb[3] - gb[1];
            float t0 = (mcx - an.x) / (0.1f * an.z);
            float t1 = (mcy - an.y) / (0.1f * an.w);
            float t2 = __logf(mw / an.z) / 0.2f;
            float t3 = __logf(mh / an.w) / 0.2f;
            float4 pl = *(const float4*)&refine_loc[(size_t)idx * 4];
            ploc = sl1(pl.x - t0) + sl1(pl.y - t1) + sl1(pl.z - t2) + sl1(pl.w - t3);
        } else {
            negce[idx] = ce;
        }
    }
    block_reduce2_atomic(pce, ploc, &acc[0], &acc[1]);
}

// ---------------- K3b: ODM loss (C=81), LDS-staged 64-anchor tiles ----------------------
// Phase 1: coalesced float4 global->LDS (1 KB/wave-instr). Phase 2: 8-lane-group softmax
// from LDS. 20.7 KB LDS -> 7 blocks/CU; block-level pipelining hides HBM latency.
__global__ __launch_bounds__(256) void k_odm_loss(
    const float* __restrict__ pred_conf,   // [NB*NA*81]
    const float* __restrict__ pred_loc,
    const float* __restrict__ anchors,
    const float* __restrict__ refine_loc,
    const float* __restrict__ gt_boxes,
    const int* __restrict__ match,         // ODM section
    float* __restrict__ negce,             // ODM section
    float* __restrict__ acc)               // acc[0]=pos_ce, acc[1]=loc
{
    __shared__ float s_conf[ODM_TILE_F];   // 20736 B
    int tid = threadIdx.x;
    int abase = blockIdx.x * ODM_TILE;

    // phase 1: stage tile (ODM_TILE*81 floats = 1296 float4, all contiguous)
    const float4* src = (const float4*)(pred_conf + (size_t)abase * NC);
    float4* dst = (float4*)s_conf;
    #pragma unroll
    for (int k = 0; k < 6; k++) {
        int i = tid + k * 256;
        if (i < ODM_TILE_F / 4) dst[i] = src[i];
    }
    __syncthreads();

    int lane = tid & 63;
    int wv = tid >> 6;                     // wave 0..3
    int sub = lane & 7;
    int grp = lane >> 3;
    float pce = 0.f, ploc = 0.f;
    #pragma unroll
    for (int t = 0; t < 2; t++) {
        int la = (wv << 4) + (t << 3) + grp;   // 16 anchors per wave
        int idx = abase + la;
        const float* p = s_conf + la * NC;
        float x[10];
        #pragma unroll
        for (int j = 0; j < 10; j++) x[j] = p[sub + 8 * j];
        float x80 = (sub == 0) ? p[80] : -3.0e38f;
        int m = match[idx];
        int conf = m & 0xFFFF; int g = m >> 16;

        float mx = x80;
        #pragma unroll
        for (int j = 0; j < 10; j++) mx = fmaxf(mx, x[j]);
        mx = fmaxf(mx, __shfl_xor(mx, 1));
        mx = fmaxf(mx, __shfl_xor(mx, 2));
        mx = fmaxf(mx, __shfl_xor(mx, 4));

        float s = (sub == 0) ? __expf(x80 - mx) : 0.f;
        float sel = (sub == 0 && conf == 80) ? x80 : 0.f;
        #pragma unroll
        for (int j = 0; j < 10; j++) {
            s += __expf(x[j] - mx);
            sel += (sub + 8 * j == conf) ? x[j] : 0.f;
        }
        s += __shfl_xor(s, 1);   sel += __shfl_xor(sel, 1);
        s += __shfl_xor(s, 2);   sel += __shfl_xor(sel, 2);
        s += __shfl_xor(s, 4);   sel += __shfl_xor(sel, 4);
        float ce = mx + __logf(s) - sel;

        if (sub == 0) {
            if (conf > 0) {
                pce += ce;
                negce[idx] = 0.f;
                int b = idx / NA, a = idx - b * NA;
                float4 an = *(const float4*)&anchors[(size_t)a * 4];
                float4 rl = *(const float4*)&refine_loc[(size_t)idx * 4];
                float acx = an.x + rl.x * 0.1f * an.z;
                float acy = an.y + rl.y * 0.1f * an.w;
                float aw = an.z * __expf(rl.z * 0.2f);
                float ah = an.w * __expf(rl.w * 0.2f);
                const float* gb = &gt_boxes[(size_t)(b * NG + g) * 4];
                float mcx = (gb[0] + gb[2]) * 0.5f, mcy = (gb[1] + gb[3]) * 0.5f;
                float mw = gb[2] - gb[0], mh = gb[3] - gb[1];
                float t0 = (mcx - acx) / (0.1f * aw);
                float t1 = (mcy - acy) / (0.1f * ah);
                float t2 = __logf(mw / aw) / 0.2f;
                float t3 = __logf(mh / ah) / 0.2f;
                float4 pl = *(const float4*)&pred_loc[(size_t)idx * 4];
                ploc += sl1(pl.x - t0) + sl1(pl.y - t1) + sl1(pl.z - t2) + sl1(pl.w - t3);
            } else {
                negce[idx] = ce;
            }
        }
    }
    block_reduce2_atomic(pce, ploc, &acc[0], &acc[1]);
}

// ---------------- K4: per-image hard-negative top-k sum ---------------------------------
__global__ __launch_bounds__(256) void k_topk(
    const float* __restrict__ negce,   // [2*NB*NA], positives marked 0.0
    const int* __restrict__ pos_num,   // [2*NB]
    float* __restrict__ topk)          // [2*NB]
{
    int blk = blockIdx.x;              // 2*NB
    int tid = threadIdx.x;
    __shared__ float s_val[NA];        // 65280 B
    __shared__ int s_red[4];
    __shared__ float s_redf[4];
    size_t sec = (size_t)blk * NA;
    for (int i = tid; i < NA; i += 256) s_val[i] = negce[sec + i];
    __syncthreads();
    int p = pos_num[blk];
    int k = p * 3; if (k > NA - p) k = NA - p; if (k < 10) k = 10;

    // binary search smallest x (uint bits) with count(val > x) < k  → x = k-th largest
    unsigned lo = 0u, hi = 0x7F800000u;
    while (lo < hi) {
        unsigned mid = (lo + hi) >> 1;
        float fmid = __uint_as_float(mid);
        int c = 0;
        for (int i = tid; i < NA; i += 256) c += (s_val[i] > fmid);
        #pragma unroll
        for (int o = 32; o > 0; o >>= 1) c += __shfl_down(c, o);
        if ((tid & 63) == 0) s_red[tid >> 6] = c;
        __syncthreads();
        int total = s_red[0] + s_red[1] + s_red[2] + s_red[3];
        __syncthreads();
        if (total < k) hi = mid; else lo = mid + 1;
    }
    float V = __uint_as_float(lo);
    int c = 0; float sum = 0.f;
    for (int i = tid; i < NA; i += 256) {
        float v = s_val[i];
        if (v > V) { c++; sum += v; }
    }
    #pragma unroll
    for (int o = 32; o > 0; o >>= 1) { c += __shfl_down(c, o); sum += __shfl_down(sum, o); }
    if ((tid & 63) == 0) { s_red[tid >> 6] = c; s_redf[tid >> 6] = sum; }
    __syncthreads();
    if (tid == 0) {
        int cg = s_red[0] + s_red[1] + s_red[2] + s_red[3];
        float sg = s_redf[0] + s_redf[1] + s_redf[2] + s_redf[3];
        topk[blk] = sg + (float)(k - cg) * V;
    }
}

// ---------------- K5: finalize ----------------------------------------------------------
__global__ void k_final(const float* __restrict__ acc, const int* __restrict__ pos_num,
                        const float* __restrict__ topk, float* __restrict__ out)
{
    if (threadIdx.x == 0 && blockIdx.x == 0) {
        float cls[2], loc[2];
        for (int l = 0; l < 2; l++) {
            float N = 0.f, tk = 0.f;
            for (int b = 0; b < NB; b++) {
                N += (float)pos_num[l * NB + b];
                tk += topk[l * NB + b];
            }
            cls[l] = (acc[l * 2 + 0] + tk) / N;
            loc[l] = acc[l * 2 + 1] / N;
        }
        out[0] = cls[0] + loc[0] + cls[1] + loc[1];
        out[1] = cls[1];
        out[2] = loc[1];
        out[3] = cls[0];
        out[4] = loc[0];
    }
}

extern "C" void kernel_launch(void* const* d_in, const int* in_sizes, int n_in,
                              void* d_out, int out_size, void* d_ws, size_t ws_size,
                              hipStream_t stream) {
    const float* objectness = (const float*)d_in[0];
    const float* refine_loc = (const float*)d_in[1];
    const float* pred_conf  = (const float*)d_in[2];
    const float* pred_loc   = (const float*)d_in[3];
    const float* anchors    = (const float*)d_in[4];  // [1,NA,4] -> a0
    const float* gt_boxes   = (const float*)d_in[5];
    const int*   gt_labels  = (const int*)d_in[6];

    char* w = (char*)d_ws;
    size_t off = 0;
    float* acc = (float*)(w + off); off += 8 * sizeof(float);          // 32 B [zeroed]
    int* pos_num = (int*)(w + off); off += 64 * sizeof(int);           // 256 B [zeroed]
    unsigned long long* ws_best = (unsigned long long*)(w + off);
    off += (size_t)2 * NB * NG * 8;                                    // 16 KB [zeroed]
    size_t zero_bytes = off;
    float* topk = (float*)(w + off); off += 64 * sizeof(float);
    off = (off + 15) & ~(size_t)15;
    float4* pf = (float4*)(w + off); off += (size_t)(NB + 1) * NA * 16;
    float* parea = (float*)(w + off); off += (size_t)(NB + 1) * NA * 4;
    float* ws_ov = (float*)(w + off); off += (size_t)2 * NB * NA * 4;
    unsigned char* ws_idx = (unsigned char*)(w + off); off += (size_t)2 * NB * NA;
    off = (off + 15) & ~(size_t)15;
    int* match = (int*)(w + off); off += (size_t)2 * NB * NA * 4;
    float* negce = (float*)(w + off); off += (size_t)2 * NB * NA * 4;

    hipMemsetAsync(d_ws, 0, zero_bytes, stream);

    k_decode<<<((NB + 1) * NA + 255) / 256, 256, 0, stream>>>(anchors, refine_loc, pf, parea);
    k_match_a<<<64 * 64, 256, 0, stream>>>(pf, parea, gt_boxes, ws_ov, ws_idx);
    k_match_g<<<64 * 8, 256, 0, stream>>>(pf, parea, gt_boxes, ws_best);
    k_conf<<<64 * 8, 256, 0, stream>>>(gt_labels, ws_best, ws_ov, ws_idx, match, pos_num);
    k_arm_loss<<<(NB * NA + 255) / 256, 256, 0, stream>>>(objectness, refine_loc, anchors,
                                                          gt_boxes, match, negce, acc);
    k_odm_loss<<<NB * NA / ODM_TILE, 256, 0, stream>>>(pred_conf, pred_loc, anchors,
                                                       refine_loc, gt_boxes,
                                                       match + (size_t)NB * NA,
                                                       negce + (size_t)NB * NA, acc + 2);
    k_topk<<<2 * NB, 256, 0, stream>>>(negce, pos_num, topk);
    k_final<<<1, 64, 0, stream>>>(acc, pos_num, topk, (float*)d_out);
}

// Round 5
// 372.130 us; speedup vs baseline: 1.2161x; 1.2161x over previous
//
#include <hip/hip_runtime.h>
#include <hip/hip_bf16.h>

constexpr int NB = 32;      // batch
constexpr int NA = 16320;   // anchors
constexpr int NG = 32;      // gt boxes per image
constexpr int NC = 81;      // ODM classes

__device__ __forceinline__ float sl1(float d) {
    float ad = fabsf(d);
    return ad < 1.f ? 0.5f * d * d : ad - 0.5f;
}

// ---------------- K0: decode anchors to point-form + area -------------------------------
__global__ __launch_bounds__(256) void k_decode(
    const float* __restrict__ anchors,     // [NA*4] cxcywh
    const float* __restrict__ refine_loc,  // [NB*NA*4]
    float4* __restrict__ pf,               // [(NB+1)*NA] xyxy
    float* __restrict__ parea)             // [(NB+1)*NA]
{
    int idx = blockIdx.x * 256 + threadIdx.x;
    if (idx >= (NB + 1) * NA) return;
    int row = idx / NA;
    int a = idx - row * NA;
    float4 an = *(const float4*)&anchors[(size_t)a * 4];
    float acx = an.x, acy = an.y, aw = an.z, ah = an.w;
    if (row > 0) {
        int b = row - 1;
        float4 rl = *(const float4*)&refine_loc[((size_t)b * NA + a) * 4];
        acx += rl.x * 0.1f * aw;
        acy += rl.y * 0.1f * ah;
        aw *= __expf(rl.z * 0.2f);
        ah *= __expf(rl.w * 0.2f);
    }
    float4 o;
    o.x = acx - aw * 0.5f; o.y = acy - ah * 0.5f;
    o.z = acx + aw * 0.5f; o.w = acy + ah * 0.5f;
    pf[idx] = o;
    parea[idx] = (o.z - o.x) * (o.w - o.y);
}

// ---------------- K1a: per-anchor best gt ----------------------------------------------
__global__ __launch_bounds__(256) void k_match_a(
    const float4* __restrict__ pf,
    const float* __restrict__ parea,
    const float* __restrict__ gt_boxes,    // [NB*NG*4] xyxy
    float* __restrict__ ws_ov,             // [2*NB*NA]
    unsigned char* __restrict__ ws_idx)    // [2*NB*NA]
{
    int row = blockIdx.x >> 6;             // 0..63 = lossId*32 + b
    int chunk = blockIdx.x & 63;
    int lossId = row >> 5, b = row & 31;
    int tid = threadIdx.x;
    __shared__ float4 s_gt[NG];
    __shared__ float s_ga[NG];
    if (tid < NG) {
        float4 g = *(const float4*)&gt_boxes[(size_t)(b * NG + tid) * 4];
        s_gt[tid] = g;
        s_ga[tid] = (g.z - g.x) * (g.w - g.y);
    }
    __syncthreads();
    int a = chunk * 256 + tid;
    if (a >= NA) return;
    int prow = lossId ? (1 + b) : 0;
    float4 A = pf[(size_t)prow * NA + a];
    float aarea = parea[(size_t)prow * NA + a];
    float best = -1.f; int bg = 0;
    #pragma unroll 4
    for (int g = 0; g < NG; g++) {
        float4 G = s_gt[g];
        float tlx = fmaxf(G.x, A.x);
        float tly = fmaxf(G.y, A.y);
        float brx = fminf(G.z, A.z);
        float bry = fminf(G.w, A.w);
        float w = brx - tlx; w = w > 0.f ? w : 0.f;
        float h = bry - tly; h = h > 0.f ? h : 0.f;
        float inter = w * h;
        float uni = s_ga[g] + aarea - inter;
        float ov = inter * __builtin_amdgcn_rcpf(uni);
        if (ov > best) { best = ov; bg = g; }   // strict > keeps first (smallest) g
    }
    size_t sec = (size_t)row * NA;
    ws_ov[sec + a] = best;
    ws_idx[sec + a] = (unsigned char)bg;
}

// ---------------- K1b: per-gt best anchor (2 gt per block, no atomics) ------------------
__global__ __launch_bounds__(256) void k_match_g(
    const float4* __restrict__ pf,
    const float* __restrict__ parea,
    const float* __restrict__ gt_boxes,
    unsigned long long* __restrict__ ws_best)  // [2*NB*NG]
{
    int blk = blockIdx.x;                  // 64 rows * 16 pairs
    int row = blk >> 4;
    int gpair = blk & 15;
    int lossId = row >> 5, b = row & 31;
    int g0 = gpair * 2;
    float4 G0 = *(const float4*)&gt_boxes[(size_t)(b * NG + g0) * 4];
    float4 G1 = *(const float4*)&gt_boxes[(size_t)(b * NG + g0 + 1) * 4];
    float ga0 = (G0.z - G0.x) * (G0.w - G0.y);
    float ga1 = (G1.z - G1.x) * (G1.w - G1.y);
    int prow = lossId ? (1 + b) : 0;
    const float4* P = pf + (size_t)prow * NA;
    const float* PA = parea + (size_t)prow * NA;
    unsigned long long k0 = 0ull, k1 = 0ull;
    for (int a = threadIdx.x; a < NA; a += 256) {
        float4 A = P[a];
        float aa = PA[a];
        unsigned inv_a = 0xFFFFFFFFu - (unsigned)a;
        {
            float tlx = fmaxf(G0.x, A.x), tly = fmaxf(G0.y, A.y);
            float brx = fminf(G0.z, A.z), bry = fminf(G0.w, A.w);
            float w = brx - tlx; w = w > 0.f ? w : 0.f;
            float h = bry - tly; h = h > 0.f ? h : 0.f;
            float inter = w * h;
            float ov = inter * __builtin_amdgcn_rcpf(ga0 + aa - inter);
            unsigned long long key = ((unsigned long long)__float_as_uint(ov) << 32) | inv_a;
            k0 = key > k0 ? key : k0;
        }
        {
            float tlx = fmaxf(G1.x, A.x), tly = fmaxf(G1.y, A.y);
            float brx = fminf(G1.z, A.z), bry = fminf(G1.w, A.w);
            float w = brx - tlx; w = w > 0.f ? w : 0.f;
            float h = bry - tly; h = h > 0.f ? h : 0.f;
            float inter = w * h;
            float ov = inter * __builtin_amdgcn_rcpf(ga1 + aa - inter);
            unsigned long long key = ((unsigned long long)__float_as_uint(ov) << 32) | inv_a;
            k1 = key > k1 ? key : k1;
        }
    }
    #pragma unroll
    for (int o = 32; o > 0; o >>= 1) {
        unsigned long long t0 = __shfl_down(k0, o);
        unsigned long long t1 = __shfl_down(k1, o);
        k0 = t0 > k0 ? t0 : k0;
        k1 = t1 > k1 ? t1 : k1;
    }
    __shared__ unsigned long long s0[4], s1[4];
    int w = threadIdx.x >> 6;
    if ((threadIdx.x & 63) == 0) { s0[w] = k0; s1[w] = k1; }
    __syncthreads();
    if (threadIdx.x == 0) {
        unsigned long long m0 = s0[0], m1 = s1[0];
        for (int i = 1; i < 4; i++) {
            m0 = s0[i] > m0 ? s0[i] : m0;
            m1 = s1[i] > m1 ? s1[i] : m1;
        }
        ws_best[(size_t)row * NG + g0] = m0;
        ws_best[(size_t)row * NG + g0 + 1] = m1;
    }
}

// ---------------- K2: conf assignment with guarantee override + pos count ---------------
__global__ __launch_bounds__(256) void k_conf(
    const int* __restrict__ gt_labels,     // [NB*NG]
    const unsigned long long* __restrict__ ws_best,
    const float* __restrict__ ws_ov,
    const unsigned char* __restrict__ ws_idx,
    int* __restrict__ match,               // [2*NB*NA] packed conf | g<<16
    int* __restrict__ pos_num)             // [2*NB], pre-zeroed
{
    int row = blockIdx.x >> 3;             // 64 rows
    int chunk = blockIdx.x & 7;            // 8 chunks of 2040
    int lossId = row >> 5, b = row & 31;
    int tid = threadIdx.x;
    __shared__ int s_oa[NG];
    __shared__ int s_lab[NG];
    __shared__ unsigned s_mask[512];       // NA bits = 510 words
    for (int i = tid; i < 512; i += 256) s_mask[i] = 0u;
    __syncthreads();
    if (tid < NG) {
        s_lab[tid] = lossId ? gt_labels[b * NG + tid] : 0;
        unsigned a = 0xFFFFFFFFu - (unsigned)(ws_best[(size_t)row * NG + tid] & 0xFFFFFFFFull);
        s_oa[tid] = (int)a;
        atomicOr(&s_mask[a >> 5], 1u << (a & 31));
    }
    __syncthreads();
    size_t sec = (size_t)row * NA;
    int base = chunk * 2040;
    int cnt = 0;
    for (int a = base + tid; a < base + 2040; a += 256) {
        float ov = ws_ov[sec + a];
        int g = ws_idx[sec + a];
        if (s_mask[a >> 5] & (1u << (a & 31))) {
            for (int j = NG - 1; j >= 0; j--)      // last gt wins on duplicates
                if (s_oa[j] == a) { g = j; ov = 2.0f; break; }
        }
        int conf = (ov < 0.5f) ? 0 : (s_lab[g] + 1);
        match[sec + a] = conf | (g << 16);
        cnt += (conf > 0);
    }
    #pragma unroll
    for (int o = 32; o > 0; o >>= 1) cnt += __shfl_down(cnt, o);
    __shared__ int s_c[4];
    if ((tid & 63) == 0) s_c[tid >> 6] = cnt;
    __syncthreads();
    if (tid == 0) atomicAdd(&pos_num[row], s_c[0] + s_c[1] + s_c[2] + s_c[3]);
}

__device__ __forceinline__ void block_reduce2_atomic(float v0, float v1, float* a0, float* a1) {
    #pragma unroll
    for (int o = 32; o > 0; o >>= 1) { v0 += __shfl_down(v0, o); v1 += __shfl_down(v1, o); }
    __shared__ float s0[8], s1[8];
    int w = threadIdx.x >> 6;
    if ((threadIdx.x & 63) == 0) { s0[w] = v0; s1[w] = v1; }
    __syncthreads();
    if (threadIdx.x == 0) {
        float t0 = 0.f, t1 = 0.f;
        int nw = blockDim.x >> 6;
        for (int i = 0; i < nw; i++) { t0 += s0[i]; t1 += s1[i]; }
        atomicAdd(a0, t0); atomicAdd(a1, t1);
    }
}

// ---------------- K3a: ARM loss (C=2), thread per anchor --------------------------------
__global__ __launch_bounds__(256) void k_arm_loss(
    const float* __restrict__ objectness,  // [NB*NA*2]
    const float* __restrict__ refine_loc,  // pred_loc for ARM
    const float* __restrict__ anchors,
    const float* __restrict__ gt_boxes,
    const int* __restrict__ match,         // ARM section
    float* __restrict__ negce,             // ARM section
    float* __restrict__ acc)               // acc[0]=pos_ce, acc[1]=loc
{
    int idx = blockIdx.x * 256 + threadIdx.x;
    float pce = 0.f, ploc = 0.f;
    if (idx < NB * NA) {
        int b = idx / NA, a = idx - b * NA;
        float2 x = *(const float2*)&objectness[(size_t)idx * 2];
        float mx = fmaxf(x.x, x.y);
        float s = __expf(x.x - mx) + __expf(x.y - mx);
        float lse = mx + __logf(s);
        int m = match[idx]; int conf = m & 0xFFFF; int g = m >> 16;
        float ce = lse - (conf ? x.y : x.x);
        if (conf > 0) {
            pce = ce;
            negce[idx] = 0.f;
            float4 an = *(const float4*)&anchors[(size_t)a * 4];
            const float* gb = &gt_boxes[(size_t)(b * NG + g) * 4];
            float mcx = (gb[0] + gb[2]) * 0.5f, mcy = (gb[1] + gb[3]) * 0.5f;
            float mw = gb[2] - gb[0], mh = gb[3] - gb[1];
            float t0 = (mcx - an.x) / (0.1f * an.z);
            float t1 = (mcy - an.y) / (0.1f * an.w);
            float t2 = __logf(mw / an.z) / 0.2f;
            float t3 = __logf(mh / an.w) / 0.2f;
            float4 pl = *(const float4*)&refine_loc[(size_t)idx * 4];
            ploc = sl1(pl.x - t0) + sl1(pl.y - t1) + sl1(pl.z - t2) + sl1(pl.w - t3);
        } else {
            negce[idx] = ce;
        }
    }
    block_reduce2_atomic(pce, ploc, &acc[0], &acc[1]);
}

// ---------------- K3b helper: one anchor's softmax-CE + loc (8-lane group) --------------
__device__ __forceinline__ void odm_anchor(
    int idx, const float* x, float x80, int m, int sub,
    const float* __restrict__ anchors, const float* __restrict__ refine_loc,
    const float* __restrict__ gt_boxes, const float* __restrict__ pred_loc,
    float* __restrict__ negce, float& pce, float& ploc)
{
    int conf = m & 0xFFFF; int g = m >> 16;
    float mx = x80;
    #pragma unroll
    for (int j = 0; j < 10; j++) mx = fmaxf(mx, x[j]);
    mx = fmaxf(mx, __shfl_xor(mx, 1));
    mx = fmaxf(mx, __shfl_xor(mx, 2));
    mx = fmaxf(mx, __shfl_xor(mx, 4));
    float s = (sub == 0) ? __expf(x80 - mx) : 0.f;
    float sel = (sub == 0 && conf == 80) ? x80 : 0.f;
    #pragma unroll
    for (int j = 0; j < 10; j++) {
        s += __expf(x[j] - mx);
        sel += (sub + 8 * j == conf) ? x[j] : 0.f;
    }
    s += __shfl_xor(s, 1);   sel += __shfl_xor(sel, 1);
    s += __shfl_xor(s, 2);   sel += __shfl_xor(sel, 2);
    s += __shfl_xor(s, 4);   sel += __shfl_xor(sel, 4);
    float ce = mx + __logf(s) - sel;
    if (sub == 0) {
        if (conf > 0) {
            pce += ce;
            negce[idx] = 0.f;
            int b = idx / NA, a = idx - b * NA;
            float4 an = *(const float4*)&anchors[(size_t)a * 4];
            float4 rl = *(const float4*)&refine_loc[(size_t)idx * 4];
            float acx = an.x + rl.x * 0.1f * an.z;
            float acy = an.y + rl.y * 0.1f * an.w;
            float aw = an.z * __expf(rl.z * 0.2f);
            float ah = an.w * __expf(rl.w * 0.2f);
            const float* gb = &gt_boxes[(size_t)(b * NG + g) * 4];
            float mcx = (gb[0] + gb[2]) * 0.5f, mcy = (gb[1] + gb[3]) * 0.5f;
            float mw = gb[2] - gb[0], mh = gb[3] - gb[1];
            float t0 = (mcx - acx) / (0.1f * aw);
            float t1 = (mcy - acy) / (0.1f * ah);
            float t2 = __logf(mw / aw) / 0.2f;
            float t3 = __logf(mh / ah) / 0.2f;
            float4 pl = *(const float4*)&pred_loc[(size_t)idx * 4];
            ploc += sl1(pl.x - t0) + sl1(pl.y - t1) + sl1(pl.z - t2) + sl1(pl.w - t3);
        } else {
            negce[idx] = ce;
        }
    }
}

// ---------------- K3b: ODM loss — one-shot, 16 anchors/wave, all loads hoisted ----------
__global__ __launch_bounds__(256) void k_odm_loss(
    const float* __restrict__ pred_conf,   // [NB*NA*81]
    const float* __restrict__ pred_loc,
    const float* __restrict__ anchors,
    const float* __restrict__ refine_loc,
    const float* __restrict__ gt_boxes,
    const int* __restrict__ match,         // ODM section
    float* __restrict__ negce,             // ODM section
    float* __restrict__ acc)               // acc[0]=pos_ce, acc[1]=loc
{
    int tid = threadIdx.x;
    int lane = tid & 63;
    int sub = lane & 7;                    // lane within 8-lane group
    int grp = lane >> 3;                   // anchor offset within half-tile
    int wbase = blockIdx.x * 64 + (tid >> 6) * 16;   // 16 anchors per wave
    int idxA = wbase + grp;
    int idxB = wbase + 8 + grp;

    // hoist ALL loads (22 conf floats + 2 match ints per lane) for max ILP
    const float* pA = pred_conf + (size_t)idxA * NC;
    const float* pB = pred_conf + (size_t)idxB * NC;
    float xA[10], xB[10];
    #pragma unroll
    for (int j = 0; j < 10; j++) xA[j] = pA[sub + 8 * j];
    #pragma unroll
    for (int j = 0; j < 10; j++) xB[j] = pB[sub + 8 * j];
    float xA80 = (sub == 0) ? pA[80] : -3.0e38f;
    float xB80 = (sub == 0) ? pB[80] : -3.0e38f;
    int mA = match[idxA];
    int mB = match[idxB];

    float pce = 0.f, ploc = 0.f;
    odm_anchor(idxA, xA, xA80, mA, sub, anchors, refine_loc, gt_boxes, pred_loc,
               negce, pce, ploc);
    odm_anchor(idxB, xB, xB80, mB, sub, anchors, refine_loc, gt_boxes, pred_loc,
               negce, pce, ploc);
    block_reduce2_atomic(pce, ploc, &acc[0], &acc[1]);
}

// ---------------- K4: per-image hard-negative top-k sum (register-resident) -------------
__global__ __launch_bounds__(256) void k_topk(
    const float* __restrict__ negce,   // [2*NB*NA], positives marked 0.0
    const int* __restrict__ pos_num,   // [2*NB]
    float* __restrict__ topk)          // [2*NB]
{
    int blk = blockIdx.x;              // 2*NB
    int tid = threadIdx.x;
    size_t sec = (size_t)blk * NA;
    float v[64];
    #pragma unroll
    for (int q = 0; q < 64; q++) {
        int i = tid + (q << 8);
        v[q] = (i < NA) ? negce[sec + i] : 0.f;
    }
    __shared__ int s_red[4];
    __shared__ float s_redf[4];
    int p = pos_num[blk];
    int k = p * 3; if (k > NA - p) k = NA - p; if (k < 10) k = 10;

    // binary search smallest x (uint bits) with count(val > x) < k  → x = k-th largest
    unsigned lo = 0u, hi = 0x7F800000u;
    while (lo < hi) {
        unsigned mid = (lo + hi) >> 1;
        float fmid = __uint_as_float(mid);
        int c = 0;
        #pragma unroll
        for (int q = 0; q < 64; q++) c += (v[q] > fmid);
        #pragma unroll
        for (int o = 32; o > 0; o >>= 1) c += __shfl_down(c, o);
        if ((tid & 63) == 0) s_red[tid >> 6] = c;
        __syncthreads();
        int total = s_red[0] + s_red[1] + s_red[2] + s_red[3];
        __syncthreads();
        if (total < k) hi = mid; else lo = mid + 1;
    }
    float V = __uint_as_float(lo);
    int c = 0; float sum = 0.f;
    #pragma unroll
    for (int q = 0; q < 64; q++) {
        if (v[q] > V) { c++; sum += v[q]; }
    }
    #pragma unroll
    for (int o = 32; o > 0; o >>= 1) { c += __shfl_down(c, o); sum += __shfl_down(sum, o); }
    if ((tid & 63) == 0) { s_red[tid >> 6] = c; s_redf[tid >> 6] = sum; }
    __syncthreads();
    if (tid == 0) {
        int cg = s_red[0] + s_red[1] + s_red[2] + s_red[3];
        float sg = s_redf[0] + s_redf[1] + s_redf[2] + s_redf[3];
        topk[blk] = sg + (float)(k - cg) * V;
    }
}

// ---------------- K5: finalize ----------------------------------------------------------
__global__ void k_final(const float* __restrict__ acc, const int* __restrict__ pos_num,
                        const float* __restrict__ topk, float* __restrict__ out)
{
    if (threadIdx.x == 0 && blockIdx.x == 0) {
        float cls[2], loc[2];
        for (int l = 0; l < 2; l++) {
            float N = 0.f, tk = 0.f;
            for (int b = 0; b < NB; b++) {
                N += (float)pos_num[l * NB + b];
                tk += topk[l * NB + b];
            }
            cls[l] = (acc[l * 2 + 0] + tk) / N;
            loc[l] = acc[l * 2 + 1] / N;
        }
        out[0] = cls[0] + loc[0] + cls[1] + loc[1];
        out[1] = cls[1];
        out[2] = loc[1];
        out[3] = cls[0];
        out[4] = loc[0];
    }
}

extern "C" void kernel_launch(void* const* d_in, const int* in_sizes, int n_in,
                              void* d_out, int out_size, void* d_ws, size_t ws_size,
                              hipStream_t stream) {
    const float* objectness = (const float*)d_in[0];
    const float* refine_loc = (const float*)d_in[1];
    const float* pred_conf  = (const float*)d_in[2];
    const float* pred_loc   = (const float*)d_in[3];
    const float* anchors    = (const float*)d_in[4];  // [1,NA,4] -> a0
    const float* gt_boxes   = (const float*)d_in[5];
    const int*   gt_labels  = (const int*)d_in[6];

    char* w = (char*)d_ws;
    size_t off = 0;
    float* acc = (float*)(w + off); off += 8 * sizeof(float);          // 32 B [zeroed]
    int* pos_num = (int*)(w + off); off += 64 * sizeof(int);           // 256 B [zeroed]
    size_t zero_bytes = off;
    float* topk = (float*)(w + off); off += 64 * sizeof(float);
    unsigned long long* ws_best = (unsigned long long*)(w + off);
    off += (size_t)2 * NB * NG * 8;                                    // fully written by k_match_g
    off = (off + 15) & ~(size_t)15;
    float4* pf = (float4*)(w + off); off += (size_t)(NB + 1) * NA * 16;
    float* parea = (float*)(w + off); off += (size_t)(NB + 1) * NA * 4;
    float* ws_ov = (float*)(w + off); off += (size_t)2 * NB * NA * 4;
    unsigned char* ws_idx = (unsigned char*)(w + off); off += (size_t)2 * NB * NA;
    off = (off + 15) & ~(size_t)15;
    int* match = (int*)(w + off); off += (size_t)2 * NB * NA * 4;
    float* negce = (float*)(w + off); off += (size_t)2 * NB * NA * 4;

    hipMemsetAsync(d_ws, 0, zero_bytes, stream);

    k_decode<<<((NB + 1) * NA + 255) / 256, 256, 0, stream>>>(anchors, refine_loc, pf, parea);
    k_match_a<<<64 * 64, 256, 0, stream>>>(pf, parea, gt_boxes, ws_ov, ws_idx);
    k_match_g<<<64 * 16, 256, 0, stream>>>(pf, parea, gt_boxes, ws_best);
    k_conf<<<64 * 8, 256, 0, stream>>>(gt_labels, ws_best, ws_ov, ws_idx, match, pos_num);
    k_arm_loss<<<(NB * NA + 255) / 256, 256, 0, stream>>>(objectness, refine_loc, anchors,
                                                          gt_boxes, match, negce, acc);
    k_odm_loss<<<NB * NA / 64, 256, 0, stream>>>(pred_conf, pred_loc, anchors, refine_loc,
                                                 gt_boxes, match + (size_t)NB * NA,
                                                 negce + (size_t)NB * NA, acc + 2);
    k_topk<<<2 * NB, 256, 0, stream>>>(negce, pos_num, topk);
    k_final<<<1, 64, 0, stream>>>(acc, pos_num, topk, (float*)d_out);
}

// Round 6
// 143.158 us; speedup vs baseline: 3.1611x; 2.5994x over previous
//
#include <hip/hip_runtime.h>
#include <hip/hip_bf16.h>

constexpr int NB = 32;      // batch
constexpr int NA = 16320;   // anchors
constexpr int NG = 32;      // gt boxes per image
constexpr int NC = 81;      // ODM classes
constexpr int ARM_GRID = 1024;
constexpr int ODM_GRID = 2048;

__device__ __forceinline__ float sl1(float d) {
    float ad = fabsf(d);
    return ad < 1.f ? 0.5f * d * d : ad - 0.5f;
}

// ---------------- K0: decode anchors to point-form + area -------------------------------
__global__ __launch_bounds__(256) void k_decode(
    const float* __restrict__ anchors,     // [NA*4] cxcywh
    const float* __restrict__ refine_loc,  // [NB*NA*4]
    float4* __restrict__ pf,               // [(NB+1)*NA] xyxy
    float* __restrict__ parea)             // [(NB+1)*NA]
{
    int idx = blockIdx.x * 256 + threadIdx.x;
    if (idx >= (NB + 1) * NA) return;
    int row = idx / NA;
    int a = idx - row * NA;
    float4 an = *(const float4*)&anchors[(size_t)a * 4];
    float acx = an.x, acy = an.y, aw = an.z, ah = an.w;
    if (row > 0) {
        int b = row - 1;
        float4 rl = *(const float4*)&refine_loc[((size_t)b * NA + a) * 4];
        acx += rl.x * 0.1f * aw;
        acy += rl.y * 0.1f * ah;
        aw *= __expf(rl.z * 0.2f);
        ah *= __expf(rl.w * 0.2f);
    }
    float4 o;
    o.x = acx - aw * 0.5f; o.y = acy - ah * 0.5f;
    o.z = acx + aw * 0.5f; o.w = acy + ah * 0.5f;
    pf[idx] = o;
    parea[idx] = (o.z - o.x) * (o.w - o.y);
}

// ---------------- K1a: per-anchor best gt ----------------------------------------------
__global__ __launch_bounds__(256) void k_match_a(
    const float4* __restrict__ pf,
    const float* __restrict__ parea,
    const float* __restrict__ gt_boxes,    // [NB*NG*4] xyxy
    float* __restrict__ ws_ov,             // [2*NB*NA]
    unsigned char* __restrict__ ws_idx)    // [2*NB*NA]
{
    int row = blockIdx.x >> 6;             // 0..63 = lossId*32 + b
    int chunk = blockIdx.x & 63;
    int lossId = row >> 5, b = row & 31;
    int tid = threadIdx.x;
    __shared__ float4 s_gt[NG];
    __shared__ float s_ga[NG];
    if (tid < NG) {
        float4 g = *(const float4*)&gt_boxes[(size_t)(b * NG + tid) * 4];
        s_gt[tid] = g;
        s_ga[tid] = (g.z - g.x) * (g.w - g.y);
    }
    __syncthreads();
    int a = chunk * 256 + tid;
    if (a >= NA) return;
    int prow = lossId ? (1 + b) : 0;
    float4 A = pf[(size_t)prow * NA + a];
    float aarea = parea[(size_t)prow * NA + a];
    float best = -1.f; int bg = 0;
    #pragma unroll 4
    for (int g = 0; g < NG; g++) {
        float4 G = s_gt[g];
        float tlx = fmaxf(G.x, A.x);
        float tly = fmaxf(G.y, A.y);
        float brx = fminf(G.z, A.z);
        float bry = fminf(G.w, A.w);
        float w = brx - tlx; w = w > 0.f ? w : 0.f;
        float h = bry - tly; h = h > 0.f ? h : 0.f;
        float inter = w * h;
        float uni = s_ga[g] + aarea - inter;
        float ov = inter * __builtin_amdgcn_rcpf(uni);
        if (ov > best) { best = ov; bg = g; }   // strict > keeps first (smallest) g
    }
    size_t sec = (size_t)row * NA;
    ws_ov[sec + a] = best;
    ws_idx[sec + a] = (unsigned char)bg;
}

// ---------------- K1b: per-gt best anchor (2 gt per block, no atomics) ------------------
__global__ __launch_bounds__(256) void k_match_g(
    const float4* __restrict__ pf,
    const float* __restrict__ parea,
    const float* __restrict__ gt_boxes,
    unsigned long long* __restrict__ ws_best)  // [2*NB*NG]
{
    int blk = blockIdx.x;                  // 64 rows * 16 pairs
    int row = blk >> 4;
    int gpair = blk & 15;
    int lossId = row >> 5, b = row & 31;
    int g0 = gpair * 2;
    float4 G0 = *(const float4*)&gt_boxes[(size_t)(b * NG + g0) * 4];
    float4 G1 = *(const float4*)&gt_boxes[(size_t)(b * NG + g0 + 1) * 4];
    float ga0 = (G0.z - G0.x) * (G0.w - G0.y);
    float ga1 = (G1.z - G1.x) * (G1.w - G1.y);
    int prow = lossId ? (1 + b) : 0;
    const float4* P = pf + (size_t)prow * NA;
    const float* PA = parea + (size_t)prow * NA;
    unsigned long long k0 = 0ull, k1 = 0ull;
    for (int a = threadIdx.x; a < NA; a += 256) {
        float4 A = P[a];
        float aa = PA[a];
        unsigned inv_a = 0xFFFFFFFFu - (unsigned)a;
        {
            float tlx = fmaxf(G0.x, A.x), tly = fmaxf(G0.y, A.y);
            float brx = fminf(G0.z, A.z), bry = fminf(G0.w, A.w);
            float w = brx - tlx; w = w > 0.f ? w : 0.f;
            float h = bry - tly; h = h > 0.f ? h : 0.f;
            float inter = w * h;
            float ov = inter * __builtin_amdgcn_rcpf(ga0 + aa - inter);
            unsigned long long key = ((unsigned long long)__float_as_uint(ov) << 32) | inv_a;
            k0 = key > k0 ? key : k0;
        }
        {
            float tlx = fmaxf(G1.x, A.x), tly = fmaxf(G1.y, A.y);
            float brx = fminf(G1.z, A.z), bry = fminf(G1.w, A.w);
            float w = brx - tlx; w = w > 0.f ? w : 0.f;
            float h = bry - tly; h = h > 0.f ? h : 0.f;
            float inter = w * h;
            float ov = inter * __builtin_amdgcn_rcpf(ga1 + aa - inter);
            unsigned long long key = ((unsigned long long)__float_as_uint(ov) << 32) | inv_a;
            k1 = key > k1 ? key : k1;
        }
    }
    #pragma unroll
    for (int o = 32; o > 0; o >>= 1) {
        unsigned long long t0 = __shfl_down(k0, o);
        unsigned long long t1 = __shfl_down(k1, o);
        k0 = t0 > k0 ? t0 : k0;
        k1 = t1 > k1 ? t1 : k1;
    }
    __shared__ unsigned long long s0[4], s1[4];
    int w = threadIdx.x >> 6;
    if ((threadIdx.x & 63) == 0) { s0[w] = k0; s1[w] = k1; }
    __syncthreads();
    if (threadIdx.x == 0) {
        unsigned long long m0 = s0[0], m1 = s1[0];
        for (int i = 1; i < 4; i++) {
            m0 = s0[i] > m0 ? s0[i] : m0;
            m1 = s1[i] > m1 ? s1[i] : m1;
        }
        ws_best[(size_t)row * NG + g0] = m0;
        ws_best[(size_t)row * NG + g0 + 1] = m1;
    }
}

// ---------------- K2: conf assignment with guarantee override + pos count ---------------
__global__ __launch_bounds__(256) void k_conf(
    const int* __restrict__ gt_labels,     // [NB*NG]
    const unsigned long long* __restrict__ ws_best,
    const float* __restrict__ ws_ov,
    const unsigned char* __restrict__ ws_idx,
    int* __restrict__ match,               // [2*NB*NA] packed conf | g<<16
    int* __restrict__ pos_num)             // [2*NB], pre-zeroed
{
    int row = blockIdx.x >> 3;             // 64 rows
    int chunk = blockIdx.x & 7;            // 8 chunks of 2040
    int lossId = row >> 5, b = row & 31;
    int tid = threadIdx.x;
    __shared__ int s_oa[NG];
    __shared__ int s_lab[NG];
    __shared__ unsigned s_mask[512];       // NA bits = 510 words
    for (int i = tid; i < 512; i += 256) s_mask[i] = 0u;
    __syncthreads();
    if (tid < NG) {
        s_lab[tid] = lossId ? gt_labels[b * NG + tid] : 0;
        unsigned a = 0xFFFFFFFFu - (unsigned)(ws_best[(size_t)row * NG + tid] & 0xFFFFFFFFull);
        s_oa[tid] = (int)a;
        atomicOr(&s_mask[a >> 5], 1u << (a & 31));
    }
    __syncthreads();
    size_t sec = (size_t)row * NA;
    int base = chunk * 2040;
    int cnt = 0;
    for (int a = base + tid; a < base + 2040; a += 256) {
        float ov = ws_ov[sec + a];
        int g = ws_idx[sec + a];
        if (s_mask[a >> 5] & (1u << (a & 31))) {
            for (int j = NG - 1; j >= 0; j--)      // last gt wins on duplicates
                if (s_oa[j] == a) { g = j; ov = 2.0f; break; }
        }
        int conf = (ov < 0.5f) ? 0 : (s_lab[g] + 1);
        match[sec + a] = conf | (g << 16);
        cnt += (conf > 0);
    }
    #pragma unroll
    for (int o = 32; o > 0; o >>= 1) cnt += __shfl_down(cnt, o);
    __shared__ int s_c[4];
    if ((tid & 63) == 0) s_c[tid >> 6] = cnt;
    __syncthreads();
    if (tid == 0) atomicAdd(&pos_num[row], s_c[0] + s_c[1] + s_c[2] + s_c[3]);
}

// block-level (ce,loc) reduction; result valid on tid 0; NO global atomics
__device__ __forceinline__ void block_reduce2_store(float v0, float v1, float2* dst) {
    #pragma unroll
    for (int o = 32; o > 0; o >>= 1) { v0 += __shfl_down(v0, o); v1 += __shfl_down(v1, o); }
    __shared__ float s0[4], s1[4];
    int w = threadIdx.x >> 6;
    if ((threadIdx.x & 63) == 0) { s0[w] = v0; s1[w] = v1; }
    __syncthreads();
    if (threadIdx.x == 0) {
        float t0 = 0.f, t1 = 0.f;
        #pragma unroll
        for (int i = 0; i < 4; i++) { t0 += s0[i]; t1 += s1[i]; }
        *dst = make_float2(t0, t1);
    }
}

// ---------------- K3a: ARM loss (C=2), grid-stride, partial writes ----------------------
__global__ __launch_bounds__(256) void k_arm_loss(
    const float* __restrict__ objectness,  // [NB*NA*2]
    const float* __restrict__ refine_loc,  // pred_loc for ARM
    const float* __restrict__ anchors,
    const float* __restrict__ gt_boxes,
    const int* __restrict__ match,         // ARM section
    float* __restrict__ negce,             // ARM section
    float2* __restrict__ partial)          // [ARM_GRID]
{
    float pce = 0.f, ploc = 0.f;
    for (int idx = blockIdx.x * 256 + threadIdx.x; idx < NB * NA; idx += ARM_GRID * 256) {
        int b = idx / NA, a = idx - b * NA;
        float2 x = *(const float2*)&objectness[(size_t)idx * 2];
        float mx = fmaxf(x.x, x.y);
        float s = __expf(x.x - mx) + __expf(x.y - mx);
        float lse = mx + __logf(s);
        int m = match[idx]; int conf = m & 0xFFFF; int g = m >> 16;
        float ce = lse - (conf ? x.y : x.x);
        if (conf > 0) {
            pce += ce;
            negce[idx] = 0.f;
            float4 an = *(const float4*)&anchors[(size_t)a * 4];
            const float* gb = &gt_boxes[(size_t)(b * NG + g) * 4];
            float mcx = (gb[0] + gb[2]) * 0.5f, mcy = (gb[1] + gb[3]) * 0.5f;
            float mw = gb[2] - gb[0], mh = gb[3] - gb[1];
            float t0 = (mcx - an.x) / (0.1f * an.z);
            float t1 = (mcy - an.y) / (0.1f * an.w);
            float t2 = __logf(mw / an.z) / 0.2f;
            float t3 = __logf(mh / an.w) / 0.2f;
            float4 pl = *(const float4*)&refine_loc[(size_t)idx * 4];
            ploc += sl1(pl.x - t0) + sl1(pl.y - t1) + sl1(pl.z - t2) + sl1(pl.w - t3);
        } else {
            negce[idx] = ce;
        }
    }
    block_reduce2_store(pce, ploc, &partial[blockIdx.x]);
}

// ---------------- K3b helper: one anchor's softmax-CE + loc (8-lane group) --------------
__device__ __forceinline__ void odm_anchor(
    int idx, const float* x, float x80, int m, int sub,
    const float* __restrict__ anchors, const float* __restrict__ refine_loc,
    const float* __restrict__ gt_boxes, const float* __restrict__ pred_loc,
    float* __restrict__ negce, float& pce, float& ploc)
{
    int conf = m & 0xFFFF; int g = m >> 16;
    float mx = x80;
    #pragma unroll
    for (int j = 0; j < 10; j++) mx = fmaxf(mx, x[j]);
    mx = fmaxf(mx, __shfl_xor(mx, 1));
    mx = fmaxf(mx, __shfl_xor(mx, 2));
    mx = fmaxf(mx, __shfl_xor(mx, 4));
    float s = (sub == 0) ? __expf(x80 - mx) : 0.f;
    float sel = (sub == 0 && conf == 80) ? x80 : 0.f;
    #pragma unroll
    for (int j = 0; j < 10; j++) {
        s += __expf(x[j] - mx);
        sel += (sub + 8 * j == conf) ? x[j] : 0.f;
    }
    s += __shfl_xor(s, 1);   sel += __shfl_xor(sel, 1);
    s += __shfl_xor(s, 2);   sel += __shfl_xor(sel, 2);
    s += __shfl_xor(s, 4);   sel += __shfl_xor(sel, 4);
    float ce = mx + __logf(s) - sel;
    if (sub == 0) {
        if (conf > 0) {
            pce += ce;
            negce[idx] = 0.f;
            int b = idx / NA, a = idx - b * NA;
            float4 an = *(const float4*)&anchors[(size_t)a * 4];
            float4 rl = *(const float4*)&refine_loc[(size_t)idx * 4];
            float acx = an.x + rl.x * 0.1f * an.z;
            float acy = an.y + rl.y * 0.1f * an.w;
            float aw = an.z * __expf(rl.z * 0.2f);
            float ah = an.w * __expf(rl.w * 0.2f);
            const float* gb = &gt_boxes[(size_t)(b * NG + g) * 4];
            float mcx = (gb[0] + gb[2]) * 0.5f, mcy = (gb[1] + gb[3]) * 0.5f;
            float mw = gb[2] - gb[0], mh = gb[3] - gb[1];
            float t0 = (mcx - acx) / (0.1f * aw);
            float t1 = (mcy - acy) / (0.1f * ah);
            float t2 = __logf(mw / aw) / 0.2f;
            float t3 = __logf(mh / ah) / 0.2f;
            float4 pl = *(const float4*)&pred_loc[(size_t)idx * 4];
            ploc += sl1(pl.x - t0) + sl1(pl.y - t1) + sl1(pl.z - t2) + sl1(pl.w - t3);
        } else {
            negce[idx] = ce;
        }
    }
}

// ---------------- K3b: ODM loss — grid-stride + 1-deep register prefetch ----------------
__global__ __launch_bounds__(256, 4) void k_odm_loss(
    const float* __restrict__ pred_conf,   // [NB*NA*81]
    const float* __restrict__ pred_loc,
    const float* __restrict__ anchors,
    const float* __restrict__ refine_loc,
    const float* __restrict__ gt_boxes,
    const int* __restrict__ match,         // ODM section
    float* __restrict__ negce,             // ODM section
    float2* __restrict__ partial)          // [ODM_GRID]
{
    int lane = threadIdx.x & 63;
    int sub = lane & 7;
    int grp = lane >> 3;
    int wid = blockIdx.x * 4 + (threadIdx.x >> 6);
    const int NWAVE = ODM_GRID * 4;
    const int TOT = NB * NA / 8;           // 65280 groups of 8 anchors
    float pce = 0.f, ploc = 0.f;

    float x[10], x80; int m, idx;
    {   // prologue load (wid < TOT always: NWAVE=8192 <= 65280)
        idx = wid * 8 + grp;
        const float* p = pred_conf + (size_t)idx * NC;
        #pragma unroll
        for (int j = 0; j < 10; j++) x[j] = p[sub + 8 * j];
        x80 = (sub == 0) ? p[80] : -3.0e38f;
        m = match[idx];
    }
    for (int gi = wid; gi < TOT; gi += NWAVE) {
        float y[10], y80 = 0.f; int my = 0, idxy = 0;
        int nx = gi + NWAVE;
        if (nx < TOT) {                    // prefetch next tile while computing current
            idxy = nx * 8 + grp;
            const float* p = pred_conf + (size_t)idxy * NC;
            #pragma unroll
            for (int j = 0; j < 10; j++) y[j] = p[sub + 8 * j];
            y80 = (sub == 0) ? p[80] : -3.0e38f;
            my = match[idxy];
        }
        odm_anchor(idx, x, x80, m, sub, anchors, refine_loc, gt_boxes, pred_loc,
                   negce, pce, ploc);
        #pragma unroll
        for (int j = 0; j < 10; j++) x[j] = y[j];
        x80 = y80; m = my; idx = idxy;
    }
    block_reduce2_store(pce, ploc, &partial[blockIdx.x]);
}

// ---------------- K4: per-image hard-negative top-k sum (register-resident) -------------
__global__ __launch_bounds__(256) void k_topk(
    const float* __restrict__ negce,   // [2*NB*NA], positives marked 0.0
    const int* __restrict__ pos_num,   // [2*NB]
    float* __restrict__ topk)          // [2*NB]
{
    int blk = blockIdx.x;              // 2*NB
    int tid = threadIdx.x;
    size_t sec = (size_t)blk * NA;
    float v[64];
    #pragma unroll
    for (int q = 0; q < 64; q++) {
        int i = tid + (q << 8);
        v[q] = (i < NA) ? negce[sec + i] : 0.f;
    }
    __shared__ int s_red[4];
    __shared__ float s_redf[4];
    int p = pos_num[blk];
    int k = p * 3; if (k > NA - p) k = NA - p; if (k < 10) k = 10;

    // binary search smallest x (uint bits) with count(val > x) < k  → x = k-th largest
    unsigned lo = 0u, hi = 0x7F800000u;
    while (lo < hi) {
        unsigned mid = (lo + hi) >> 1;
        float fmid = __uint_as_float(mid);
        int c = 0;
        #pragma unroll
        for (int q = 0; q < 64; q++) c += (v[q] > fmid);
        #pragma unroll
        for (int o = 32; o > 0; o >>= 1) c += __shfl_down(c, o);
        if ((tid & 63) == 0) s_red[tid >> 6] = c;
        __syncthreads();
        int total = s_red[0] + s_red[1] + s_red[2] + s_red[3];
        __syncthreads();
        if (total < k) hi = mid; else lo = mid + 1;
    }
    float V = __uint_as_float(lo);
    int c = 0; float sum = 0.f;
    #pragma unroll
    for (int q = 0; q < 64; q++) {
        if (v[q] > V) { c++; sum += v[q]; }
    }
    #pragma unroll
    for (int o = 32; o > 0; o >>= 1) { c += __shfl_down(c, o); sum += __shfl_down(sum, o); }
    if ((tid & 63) == 0) { s_red[tid >> 6] = c; s_redf[tid >> 6] = sum; }
    __syncthreads();
    if (tid == 0) {
        int cg = s_red[0] + s_red[1] + s_red[2] + s_red[3];
        float sg = s_redf[0] + s_redf[1] + s_redf[2] + s_redf[3];
        topk[blk] = sg + (float)(k - cg) * V;
    }
}

// ---------------- K5: final reduce of partials + outputs --------------------------------
__global__ __launch_bounds__(256) void k_final(
    const float2* __restrict__ pArm, const float2* __restrict__ pOdm,
    const int* __restrict__ pos_num, const float* __restrict__ topk,
    float* __restrict__ out)
{
    int tid = threadIdx.x;
    float a0 = 0.f, a1 = 0.f, o0 = 0.f, o1 = 0.f;
    for (int i = tid; i < ARM_GRID; i += 256) { float2 v = pArm[i]; a0 += v.x; a1 += v.y; }
    for (int i = tid; i < ODM_GRID; i += 256) { float2 v = pOdm[i]; o0 += v.x; o1 += v.y; }
    #pragma unroll
    for (int o = 32; o > 0; o >>= 1) {
        a0 += __shfl_down(a0, o); a1 += __shfl_down(a1, o);
        o0 += __shfl_down(o0, o); o1 += __shfl_down(o1, o);
    }
    __shared__ float s[4][4];
    if ((tid & 63) == 0) {
        int w = tid >> 6;
        s[w][0] = a0; s[w][1] = a1; s[w][2] = o0; s[w][3] = o1;
    }
    __syncthreads();
    if (tid == 0) {
        float armce = 0.f, armloc = 0.f, odmce = 0.f, odmloc = 0.f;
        #pragma unroll
        for (int i = 0; i < 4; i++) {
            armce += s[i][0]; armloc += s[i][1]; odmce += s[i][2]; odmloc += s[i][3];
        }
        float N0 = 0.f, N1 = 0.f, tk0 = 0.f, tk1 = 0.f;
        for (int b = 0; b < NB; b++) {
            N0 += (float)pos_num[b];        tk0 += topk[b];
            N1 += (float)pos_num[NB + b];   tk1 += topk[NB + b];
        }
        float cls0 = (armce + tk0) / N0, loc0 = armloc / N0;
        float cls1 = (odmce + tk1) / N1, loc1 = odmloc / N1;
        out[0] = cls0 + loc0 + cls1 + loc1;
        out[1] = cls1;
        out[2] = loc1;
        out[3] = cls0;
        out[4] = loc0;
    }
}

extern "C" void kernel_launch(void* const* d_in, const int* in_sizes, int n_in,
                              void* d_out, int out_size, void* d_ws, size_t ws_size,
                              hipStream_t stream) {
    const float* objectness = (const float*)d_in[0];
    const float* refine_loc = (const float*)d_in[1];
    const float* pred_conf  = (const float*)d_in[2];
    const float* pred_loc   = (const float*)d_in[3];
    const float* anchors    = (const float*)d_in[4];  // [1,NA,4] -> a0
    const float* gt_boxes   = (const float*)d_in[5];
    const int*   gt_labels  = (const int*)d_in[6];

    char* w = (char*)d_ws;
    size_t off = 0;
    int* pos_num = (int*)(w + off); off += 64 * sizeof(int);           // [zeroed]
    size_t zero_bytes = off;
    float* topk = (float*)(w + off); off += 64 * sizeof(float);
    off = (off + 15) & ~(size_t)15;
    float2* pArm = (float2*)(w + off); off += (size_t)ARM_GRID * 8;
    float2* pOdm = (float2*)(w + off); off += (size_t)ODM_GRID * 8;
    unsigned long long* ws_best = (unsigned long long*)(w + off);
    off += (size_t)2 * NB * NG * 8;                                    // fully written
    off = (off + 15) & ~(size_t)15;
    float4* pf = (float4*)(w + off); off += (size_t)(NB + 1) * NA * 16;
    float* parea = (float*)(w + off); off += (size_t)(NB + 1) * NA * 4;
    float* ws_ov = (float*)(w + off); off += (size_t)2 * NB * NA * 4;
    unsigned char* ws_idx = (unsigned char*)(w + off); off += (size_t)2 * NB * NA;
    off = (off + 15) & ~(size_t)15;
    int* match = (int*)(w + off); off += (size_t)2 * NB * NA * 4;
    float* negce = (float*)(w + off); off += (size_t)2 * NB * NA * 4;

    hipMemsetAsync(d_ws, 0, zero_bytes, stream);

    k_decode<<<((NB + 1) * NA + 255) / 256, 256, 0, stream>>>(anchors, refine_loc, pf, parea);
    k_match_a<<<64 * 64, 256, 0, stream>>>(pf, parea, gt_boxes, ws_ov, ws_idx);
    k_match_g<<<64 * 16, 256, 0, stream>>>(pf, parea, gt_boxes, ws_best);
    k_conf<<<64 * 8, 256, 0, stream>>>(gt_labels, ws_best, ws_ov, ws_idx, match, pos_num);
    k_arm_loss<<<ARM_GRID, 256, 0, stream>>>(objectness, refine_loc, anchors,
                                             gt_boxes, match, negce, pArm);
    k_odm_loss<<<ODM_GRID, 256, 0, stream>>>(pred_conf, pred_loc, anchors, refine_loc,
                                             gt_boxes, match + (size_t)NB * NA,
                                             negce + (size_t)NB * NA, pOdm);
    k_topk<<<2 * NB, 256, 0, stream>>>(negce, pos_num, topk);
    k_final<<<1, 256, 0, stream>>>(pArm, pOdm, pos_num, topk, (float*)d_out);
}

// Round 7
// 137.787 us; speedup vs baseline: 3.2844x; 1.0390x over previous
//
#include <hip/hip_runtime.h>
#include <hip/hip_bf16.h>

constexpr int NB = 32;      // batch
constexpr int NA = 16320;   // anchors
constexpr int NG = 32;      // gt boxes per image
constexpr int NC = 81;      // ODM classes
constexpr int ARM_GRID = 1024;
constexpr int ODM_GRID = 2048;

__device__ __forceinline__ float sl1(float d) {
    float ad = fabsf(d);
    return ad < 1.f ? 0.5f * d * d : ad - 0.5f;
}

// ---------------- K0: decode anchors to point-form + area -------------------------------
__global__ __launch_bounds__(256) void k_decode(
    const float* __restrict__ anchors,     // [NA*4] cxcywh
    const float* __restrict__ refine_loc,  // [NB*NA*4]
    float4* __restrict__ pf,               // [(NB+1)*NA] xyxy
    float* __restrict__ parea)             // [(NB+1)*NA]
{
    int idx = blockIdx.x * 256 + threadIdx.x;
    if (idx >= (NB + 1) * NA) return;
    int row = idx / NA;
    int a = idx - row * NA;
    float4 an = *(const float4*)&anchors[(size_t)a * 4];
    float acx = an.x, acy = an.y, aw = an.z, ah = an.w;
    if (row > 0) {
        int b = row - 1;
        float4 rl = *(const float4*)&refine_loc[((size_t)b * NA + a) * 4];
        acx += rl.x * 0.1f * aw;
        acy += rl.y * 0.1f * ah;
        aw *= __expf(rl.z * 0.2f);
        ah *= __expf(rl.w * 0.2f);
    }
    float4 o;
    o.x = acx - aw * 0.5f; o.y = acy - ah * 0.5f;
    o.z = acx + aw * 0.5f; o.w = acy + ah * 0.5f;
    pf[idx] = o;
    parea[idx] = (o.z - o.x) * (o.w - o.y);
}

// ---------------- K1a: per-anchor best gt ----------------------------------------------
__global__ __launch_bounds__(256) void k_match_a(
    const float4* __restrict__ pf,
    const float* __restrict__ parea,
    const float* __restrict__ gt_boxes,    // [NB*NG*4] xyxy
    float* __restrict__ ws_ov,             // [2*NB*NA]
    unsigned char* __restrict__ ws_idx)    // [2*NB*NA]
{
    int row = blockIdx.x >> 6;             // 0..63 = lossId*32 + b
    int chunk = blockIdx.x & 63;
    int lossId = row >> 5, b = row & 31;
    int tid = threadIdx.x;
    __shared__ float4 s_gt[NG];
    __shared__ float s_ga[NG];
    if (tid < NG) {
        float4 g = *(const float4*)&gt_boxes[(size_t)(b * NG + tid) * 4];
        s_gt[tid] = g;
        s_ga[tid] = (g.z - g.x) * (g.w - g.y);
    }
    __syncthreads();
    int a = chunk * 256 + tid;
    if (a >= NA) return;
    int prow = lossId ? (1 + b) : 0;
    float4 A = pf[(size_t)prow * NA + a];
    float aarea = parea[(size_t)prow * NA + a];
    float best = -1.f; int bg = 0;
    #pragma unroll 4
    for (int g = 0; g < NG; g++) {
        float4 G = s_gt[g];
        float tlx = fmaxf(G.x, A.x);
        float tly = fmaxf(G.y, A.y);
        float brx = fminf(G.z, A.z);
        float bry = fminf(G.w, A.w);
        float w = brx - tlx; w = w > 0.f ? w : 0.f;
        float h = bry - tly; h = h > 0.f ? h : 0.f;
        float inter = w * h;
        float uni = s_ga[g] + aarea - inter;
        float ov = inter * __builtin_amdgcn_rcpf(uni);
        if (ov > best) { best = ov; bg = g; }   // strict > keeps first (smallest) g
    }
    size_t sec = (size_t)row * NA;
    ws_ov[sec + a] = best;
    ws_idx[sec + a] = (unsigned char)bg;
}

// ---------------- K1b: per-gt best anchor (2 gt per block, no atomics) ------------------
__global__ __launch_bounds__(256) void k_match_g(
    const float4* __restrict__ pf,
    const float* __restrict__ parea,
    const float* __restrict__ gt_boxes,
    unsigned long long* __restrict__ ws_best)  // [2*NB*NG]
{
    int blk = blockIdx.x;                  // 64 rows * 16 pairs
    int row = blk >> 4;
    int gpair = blk & 15;
    int lossId = row >> 5, b = row & 31;
    int g0 = gpair * 2;
    float4 G0 = *(const float4*)&gt_boxes[(size_t)(b * NG + g0) * 4];
    float4 G1 = *(const float4*)&gt_boxes[(size_t)(b * NG + g0 + 1) * 4];
    float ga0 = (G0.z - G0.x) * (G0.w - G0.y);
    float ga1 = (G1.z - G1.x) * (G1.w - G1.y);
    int prow = lossId ? (1 + b) : 0;
    const float4* P = pf + (size_t)prow * NA;
    const float* PA = parea + (size_t)prow * NA;
    unsigned long long k0 = 0ull, k1 = 0ull;
    for (int a = threadIdx.x; a < NA; a += 256) {
        float4 A = P[a];
        float aa = PA[a];
        unsigned inv_a = 0xFFFFFFFFu - (unsigned)a;
        {
            float tlx = fmaxf(G0.x, A.x), tly = fmaxf(G0.y, A.y);
            float brx = fminf(G0.z, A.z), bry = fminf(G0.w, A.w);
            float w = brx - tlx; w = w > 0.f ? w : 0.f;
            float h = bry - tly; h = h > 0.f ? h : 0.f;
            float inter = w * h;
            float ov = inter * __builtin_amdgcn_rcpf(ga0 + aa - inter);
            unsigned long long key = ((unsigned long long)__float_as_uint(ov) << 32) | inv_a;
            k0 = key > k0 ? key : k0;
        }
        {
            float tlx = fmaxf(G1.x, A.x), tly = fmaxf(G1.y, A.y);
            float brx = fminf(G1.z, A.z), bry = fminf(G1.w, A.w);
            float w = brx - tlx; w = w > 0.f ? w : 0.f;
            float h = bry - tly; h = h > 0.f ? h : 0.f;
            float inter = w * h;
            float ov = inter * __builtin_amdgcn_rcpf(ga1 + aa - inter);
            unsigned long long key = ((unsigned long long)__float_as_uint(ov) << 32) | inv_a;
            k1 = key > k1 ? key : k1;
        }
    }
    #pragma unroll
    for (int o = 32; o > 0; o >>= 1) {
        unsigned long long t0 = __shfl_down(k0, o);
        unsigned long long t1 = __shfl_down(k1, o);
        k0 = t0 > k0 ? t0 : k0;
        k1 = t1 > k1 ? t1 : k1;
    }
    __shared__ unsigned long long s0[4], s1[4];
    int w = threadIdx.x >> 6;
    if ((threadIdx.x & 63) == 0) { s0[w] = k0; s1[w] = k1; }
    __syncthreads();
    if (threadIdx.x == 0) {
        unsigned long long m0 = s0[0], m1 = s1[0];
        for (int i = 1; i < 4; i++) {
            m0 = s0[i] > m0 ? s0[i] : m0;
            m1 = s1[i] > m1 ? s1[i] : m1;
        }
        ws_best[(size_t)row * NG + g0] = m0;
        ws_best[(size_t)row * NG + g0 + 1] = m1;
    }
}

// ---------------- K2: conf assignment + per-chunk pos count (plain store, no memset) ----
__global__ __launch_bounds__(256) void k_conf(
    const int* __restrict__ gt_labels,     // [NB*NG]
    const unsigned long long* __restrict__ ws_best,
    const float* __restrict__ ws_ov,
    const unsigned char* __restrict__ ws_idx,
    int* __restrict__ match,               // [2*NB*NA] packed conf | g<<16
    int* __restrict__ pos_cnt)             // [64*8] per-(row,chunk) counts
{
    int row = blockIdx.x >> 3;             // 64 rows
    int chunk = blockIdx.x & 7;            // 8 chunks of 2040
    int lossId = row >> 5, b = row & 31;
    int tid = threadIdx.x;
    __shared__ int s_oa[NG];
    __shared__ int s_lab[NG];
    __shared__ unsigned s_mask[512];       // NA bits = 510 words
    for (int i = tid; i < 512; i += 256) s_mask[i] = 0u;
    __syncthreads();
    if (tid < NG) {
        s_lab[tid] = lossId ? gt_labels[b * NG + tid] : 0;
        unsigned a = 0xFFFFFFFFu - (unsigned)(ws_best[(size_t)row * NG + tid] & 0xFFFFFFFFull);
        s_oa[tid] = (int)a;
        atomicOr(&s_mask[a >> 5], 1u << (a & 31));
    }
    __syncthreads();
    size_t sec = (size_t)row * NA;
    int base = chunk * 2040;
    int cnt = 0;
    for (int a = base + tid; a < base + 2040; a += 256) {
        float ov = ws_ov[sec + a];
        int g = ws_idx[sec + a];
        if (s_mask[a >> 5] & (1u << (a & 31))) {
            for (int j = NG - 1; j >= 0; j--)      // last gt wins on duplicates
                if (s_oa[j] == a) { g = j; ov = 2.0f; break; }
        }
        int conf = (ov < 0.5f) ? 0 : (s_lab[g] + 1);
        match[sec + a] = conf | (g << 16);
        cnt += (conf > 0);
    }
    #pragma unroll
    for (int o = 32; o > 0; o >>= 1) cnt += __shfl_down(cnt, o);
    __shared__ int s_c[4];
    if ((tid & 63) == 0) s_c[tid >> 6] = cnt;
    __syncthreads();
    if (tid == 0) pos_cnt[blockIdx.x] = s_c[0] + s_c[1] + s_c[2] + s_c[3];
}

// block-level (ce,loc) reduction; result valid on tid 0; NO global atomics
__device__ __forceinline__ void block_reduce2_store(float v0, float v1, float2* dst) {
    #pragma unroll
    for (int o = 32; o > 0; o >>= 1) { v0 += __shfl_down(v0, o); v1 += __shfl_down(v1, o); }
    __shared__ float s0[4], s1[4];
    int w = threadIdx.x >> 6;
    if ((threadIdx.x & 63) == 0) { s0[w] = v0; s1[w] = v1; }
    __syncthreads();
    if (threadIdx.x == 0) {
        float t0 = 0.f, t1 = 0.f;
        #pragma unroll
        for (int i = 0; i < 4; i++) { t0 += s0[i]; t1 += s1[i]; }
        *dst = make_float2(t0, t1);
    }
}

// ---------------- K3a: ARM loss (C=2), grid-stride, partial writes ----------------------
__global__ __launch_bounds__(256) void k_arm_loss(
    const float* __restrict__ objectness,  // [NB*NA*2]
    const float* __restrict__ refine_loc,  // pred_loc for ARM
    const float* __restrict__ anchors,
    const float* __restrict__ gt_boxes,
    const int* __restrict__ match,         // ARM section
    float* __restrict__ negce,             // ARM section
    float2* __restrict__ partial)          // [ARM_GRID]
{
    float pce = 0.f, ploc = 0.f;
    for (int idx = blockIdx.x * 256 + threadIdx.x; idx < NB * NA; idx += ARM_GRID * 256) {
        int b = idx / NA, a = idx - b * NA;
        float2 x = *(const float2*)&objectness[(size_t)idx * 2];
        float mx = fmaxf(x.x, x.y);
        float s = __expf(x.x - mx) + __expf(x.y - mx);
        float lse = mx + __logf(s);
        int m = match[idx]; int conf = m & 0xFFFF; int g = m >> 16;
        float ce = lse - (conf ? x.y : x.x);
        if (conf > 0) {
            pce += ce;
            negce[idx] = 0.f;
            float4 an = *(const float4*)&anchors[(size_t)a * 4];
            const float* gb = &gt_boxes[(size_t)(b * NG + g) * 4];
            float mcx = (gb[0] + gb[2]) * 0.5f, mcy = (gb[1] + gb[3]) * 0.5f;
            float mw = gb[2] - gb[0], mh = gb[3] - gb[1];
            float t0 = (mcx - an.x) / (0.1f * an.z);
            float t1 = (mcy - an.y) / (0.1f * an.w);
            float t2 = __logf(mw / an.z) / 0.2f;
            float t3 = __logf(mh / an.w) / 0.2f;
            float4 pl = *(const float4*)&refine_loc[(size_t)idx * 4];
            ploc += sl1(pl.x - t0) + sl1(pl.y - t1) + sl1(pl.z - t2) + sl1(pl.w - t3);
        } else {
            negce[idx] = ce;
        }
    }
    block_reduce2_store(pce, ploc, &partial[blockIdx.x]);
}

// ---------------- K3b helper: one anchor's softmax-CE + loc (8-lane group) --------------
__device__ __forceinline__ void odm_anchor(
    int idx, const float* x, float x80, int m, int sub,
    const float* __restrict__ anchors, const float* __restrict__ refine_loc,
    const float* __restrict__ gt_boxes, const float* __restrict__ pred_loc,
    float* __restrict__ negce, float& pce, float& ploc)
{
    int conf = m & 0xFFFF; int g = m >> 16;
    float mx = x80;
    #pragma unroll
    for (int j = 0; j < 10; j++) mx = fmaxf(mx, x[j]);
    mx = fmaxf(mx, __shfl_xor(mx, 1));
    mx = fmaxf(mx, __shfl_xor(mx, 2));
    mx = fmaxf(mx, __shfl_xor(mx, 4));
    float s = (sub == 0) ? __expf(x80 - mx) : 0.f;
    float sel = (sub == 0 && conf == 80) ? x80 : 0.f;
    #pragma unroll
    for (int j = 0; j < 10; j++) {
        s += __expf(x[j] - mx);
        sel += (sub + 8 * j == conf) ? x[j] : 0.f;
    }
    s += __shfl_xor(s, 1);   sel += __shfl_xor(sel, 1);
    s += __shfl_xor(s, 2);   sel += __shfl_xor(sel, 2);
    s += __shfl_xor(s, 4);   sel += __shfl_xor(sel, 4);
    float ce = mx + __logf(s) - sel;
    if (sub == 0) {
        if (conf > 0) {
            pce += ce;
            negce[idx] = 0.f;
            int b = idx / NA, a = idx - b * NA;
            float4 an = *(const float4*)&anchors[(size_t)a * 4];
            float4 rl = *(const float4*)&refine_loc[(size_t)idx * 4];
            float acx = an.x + rl.x * 0.1f * an.z;
            float acy = an.y + rl.y * 0.1f * an.w;
            float aw = an.z * __expf(rl.z * 0.2f);
            float ah = an.w * __expf(rl.w * 0.2f);
            const float* gb = &gt_boxes[(size_t)(b * NG + g) * 4];
            float mcx = (gb[0] + gb[2]) * 0.5f, mcy = (gb[1] + gb[3]) * 0.5f;
            float mw = gb[2] - gb[0], mh = gb[3] - gb[1];
            float t0 = (mcx - acx) / (0.1f * aw);
            float t1 = (mcy - acy) / (0.1f * ah);
            float t2 = __logf(mw / aw) / 0.2f;
            float t3 = __logf(mh / ah) / 0.2f;
            float4 pl = *(const float4*)&pred_loc[(size_t)idx * 4];
            ploc += sl1(pl.x - t0) + sl1(pl.y - t1) + sl1(pl.z - t2) + sl1(pl.w - t3);
        } else {
            negce[idx] = ce;
        }
    }
}

// ---------------- K3b: ODM loss — grid-stride + 1-deep register prefetch ----------------
__global__ __launch_bounds__(256, 4) void k_odm_loss(
    const float* __restrict__ pred_conf,   // [NB*NA*81]
    const float* __restrict__ pred_loc,
    const float* __restrict__ anchors,
    const float* __restrict__ refine_loc,
    const float* __restrict__ gt_boxes,
    const int* __restrict__ match,         // ODM section
    float* __restrict__ negce,             // ODM section
    float2* __restrict__ partial)          // [ODM_GRID]
{
    int lane = threadIdx.x & 63;
    int sub = lane & 7;
    int grp = lane >> 3;
    int wid = blockIdx.x * 4 + (threadIdx.x >> 6);
    const int NWAVE = ODM_GRID * 4;
    const int TOT = NB * NA / 8;           // 65280 groups of 8 anchors
    float pce = 0.f, ploc = 0.f;

    float x[10], x80; int m, idx;
    {   // prologue load (wid < TOT always: NWAVE=8192 <= 65280)
        idx = wid * 8 + grp;
        const float* p = pred_conf + (size_t)idx * NC;
        #pragma unroll
        for (int j = 0; j < 10; j++) x[j] = p[sub + 8 * j];
        x80 = (sub == 0) ? p[80] : -3.0e38f;
        m = match[idx];
    }
    for (int gi = wid; gi < TOT; gi += NWAVE) {
        float y[10], y80 = 0.f; int my = 0, idxy = 0;
        int nx = gi + NWAVE;
        if (nx < TOT) {                    // prefetch next tile while computing current
            idxy = nx * 8 + grp;
            const float* p = pred_conf + (size_t)idxy * NC;
            #pragma unroll
            for (int j = 0; j < 10; j++) y[j] = p[sub + 8 * j];
            y80 = (sub == 0) ? p[80] : -3.0e38f;
            my = match[idxy];
        }
        odm_anchor(idx, x, x80, m, sub, anchors, refine_loc, gt_boxes, pred_loc,
                   negce, pce, ploc);
        #pragma unroll
        for (int j = 0; j < 10; j++) x[j] = y[j];
        x80 = y80; m = my; idx = idxy;
    }
    block_reduce2_store(pce, ploc, &partial[blockIdx.x]);
}

// ---------------- K4: per-image hard-negative top-k sum (register-resident) -------------
__global__ __launch_bounds__(256) void k_topk(
    const float* __restrict__ negce,   // [2*NB*NA], positives marked 0.0
    const int* __restrict__ pos_cnt,   // [64*8]
    float* __restrict__ topk)          // [2*NB]
{
    int blk = blockIdx.x;              // 2*NB
    int tid = threadIdx.x;
    size_t sec = (size_t)blk * NA;
    float v[64];
    #pragma unroll
    for (int q = 0; q < 64; q++) {
        int i = tid + (q << 8);
        v[q] = (i < NA) ? negce[sec + i] : 0.f;
    }
    __shared__ int s_red[4];
    __shared__ float s_redf[4];
    int p = 0;
    #pragma unroll
    for (int j = 0; j < 8; j++) p += pos_cnt[blk * 8 + j];
    int k = p * 3; if (k > NA - p) k = NA - p; if (k < 10) k = 10;

    // binary search smallest x (uint bits) with count(val > x) < k  → x = k-th largest
    unsigned lo = 0u, hi = 0x7F800000u;
    while (lo < hi) {
        unsigned mid = (lo + hi) >> 1;
        float fmid = __uint_as_float(mid);
        int c = 0;
        #pragma unroll
        for (int q = 0; q < 64; q++) c += (v[q] > fmid);
        #pragma unroll
        for (int o = 32; o > 0; o >>= 1) c += __shfl_down(c, o);
        if ((tid & 63) == 0) s_red[tid >> 6] = c;
        __syncthreads();
        int total = s_red[0] + s_red[1] + s_red[2] + s_red[3];
        __syncthreads();
        if (total < k) hi = mid; else lo = mid + 1;
    }
    float V = __uint_as_float(lo);
    int c = 0; float sum = 0.f;
    #pragma unroll
    for (int q = 0; q < 64; q++) {
        if (v[q] > V) { c++; sum += v[q]; }
    }
    #pragma unroll
    for (int o = 32; o > 0; o >>= 1) { c += __shfl_down(c, o); sum += __shfl_down(sum, o); }
    if ((tid & 63) == 0) { s_red[tid >> 6] = c; s_redf[tid >> 6] = sum; }
    __syncthreads();
    if (tid == 0) {
        int cg = s_red[0] + s_red[1] + s_red[2] + s_red[3];
        float sg = s_redf[0] + s_redf[1] + s_redf[2] + s_redf[3];
        topk[blk] = sg + (float)(k - cg) * V;
    }
}

// ---------------- K5: final reduce of partials + outputs --------------------------------
__global__ __launch_bounds__(256) void k_final(
    const float2* __restrict__ pArm, const float2* __restrict__ pOdm,
    const int* __restrict__ pos_cnt, const float* __restrict__ topk,
    float* __restrict__ out)
{
    int tid = threadIdx.x;
    float a0 = 0.f, a1 = 0.f, o0 = 0.f, o1 = 0.f;
    for (int i = tid; i < ARM_GRID; i += 256) { float2 v = pArm[i]; a0 += v.x; a1 += v.y; }
    for (int i = tid; i < ODM_GRID; i += 256) { float2 v = pOdm[i]; o0 += v.x; o1 += v.y; }
    // pos_cnt: entries 0..255 = ARM rows, 256..511 = ODM rows
    float n0 = (float)pos_cnt[tid];
    float n1 = (float)pos_cnt[256 + tid];
    float t0 = (tid < NB) ? topk[tid] : 0.f;
    float t1 = (tid < NB) ? topk[NB + tid] : 0.f;
    #pragma unroll
    for (int o = 32; o > 0; o >>= 1) {
        a0 += __shfl_down(a0, o); a1 += __shfl_down(a1, o);
        o0 += __shfl_down(o0, o); o1 += __shfl_down(o1, o);
        n0 += __shfl_down(n0, o); n1 += __shfl_down(n1, o);
        t0 += __shfl_down(t0, o); t1 += __shfl_down(t1, o);
    }
    __shared__ float s[4][8];
    if ((tid & 63) == 0) {
        int w = tid >> 6;
        s[w][0] = a0; s[w][1] = a1; s[w][2] = o0; s[w][3] = o1;
        s[w][4] = n0; s[w][5] = n1; s[w][6] = t0; s[w][7] = t1;
    }
    __syncthreads();
    if (tid == 0) {
        float armce = 0.f, armloc = 0.f, odmce = 0.f, odmloc = 0.f;
        float N0 = 0.f, N1 = 0.f, tk0 = 0.f, tk1 = 0.f;
        #pragma unroll
        for (int i = 0; i < 4; i++) {
            armce += s[i][0]; armloc += s[i][1]; odmce += s[i][2]; odmloc += s[i][3];
            N0 += s[i][4]; N1 += s[i][5]; tk0 += s[i][6]; tk1 += s[i][7];
        }
        float cls0 = (armce + tk0) / N0, loc0 = armloc / N0;
        float cls1 = (odmce + tk1) / N1, loc1 = odmloc / N1;
        out[0] = cls0 + loc0 + cls1 + loc1;
        out[1] = cls1;
        out[2] = loc1;
        out[3] = cls0;
        out[4] = loc0;
    }
}

extern "C" void kernel_launch(void* const* d_in, const int* in_sizes, int n_in,
                              void* d_out, int out_size, void* d_ws, size_t ws_size,
                              hipStream_t stream) {
    const float* objectness = (const float*)d_in[0];
    const float* refine_loc = (const float*)d_in[1];
    const float* pred_conf  = (const float*)d_in[2];
    const float* pred_loc   = (const float*)d_in[3];
    const float* anchors    = (const float*)d_in[4];  // [1,NA,4] -> a0
    const float* gt_boxes   = (const float*)d_in[5];
    const int*   gt_labels  = (const int*)d_in[6];

    char* w = (char*)d_ws;
    size_t off = 0;
    int* pos_cnt = (int*)(w + off); off += 512 * sizeof(int);          // fully written by k_conf
    float* topk = (float*)(w + off); off += 64 * sizeof(float);
    off = (off + 15) & ~(size_t)15;
    float2* pArm = (float2*)(w + off); off += (size_t)ARM_GRID * 8;
    float2* pOdm = (float2*)(w + off); off += (size_t)ODM_GRID * 8;
    unsigned long long* ws_best = (unsigned long long*)(w + off);
    off += (size_t)2 * NB * NG * 8;                                    // fully written
    off = (off + 15) & ~(size_t)15;
    float4* pf = (float4*)(w + off); off += (size_t)(NB + 1) * NA * 16;
    float* parea = (float*)(w + off); off += (size_t)(NB + 1) * NA * 4;
    float* ws_ov = (float*)(w + off); off += (size_t)2 * NB * NA * 4;
    unsigned char* ws_idx = (unsigned char*)(w + off); off += (size_t)2 * NB * NA;
    off = (off + 15) & ~(size_t)15;
    int* match = (int*)(w + off); off += (size_t)2 * NB * NA * 4;
    float* negce = (float*)(w + off); off += (size_t)2 * NB * NA * 4;

    k_decode<<<((NB + 1) * NA + 255) / 256, 256, 0, stream>>>(anchors, refine_loc, pf, parea);
    k_match_a<<<64 * 64, 256, 0, stream>>>(pf, parea, gt_boxes, ws_ov, ws_idx);
    k_match_g<<<64 * 16, 256, 0, stream>>>(pf, parea, gt_boxes, ws_best);
    k_conf<<<64 * 8, 256, 0, stream>>>(gt_labels, ws_best, ws_ov, ws_idx, match, pos_cnt);
    k_arm_loss<<<ARM_GRID, 256, 0, stream>>>(objectness, refine_loc, anchors,
                                             gt_boxes, match, negce, pArm);
    k_odm_loss<<<ODM_GRID, 256, 0, stream>>>(pred_conf, pred_loc, anchors, refine_loc,
                                             gt_boxes, match + (size_t)NB * NA,
                                             negce + (size_t)NB * NA, pOdm);
    k_topk<<<2 * NB, 256, 0, stream>>>(negce, pos_cnt, topk);
    k_final<<<1, 256, 0, stream>>>(pArm, pOdm, pos_cnt, topk, (float*)d_out);
}

// Round 8
// 134.351 us; speedup vs baseline: 3.3683x; 1.0256x over previous
//
#include <hip/hip_runtime.h>
#include <hip/hip_bf16.h>

constexpr int NB = 32;      // batch
constexpr int NA = 16320;   // anchors
constexpr int NG = 32;      // gt boxes per image
constexpr int NC = 81;      // ODM classes
constexpr int ODM_GRID = 2048;

__device__ __forceinline__ float sl1(float d) {
    float ad = fabsf(d);
    return ad < 1.f ? 0.5f * d * d : ad - 0.5f;
}

__device__ __forceinline__ unsigned long long umax64(unsigned long long a, unsigned long long b) {
    return a > b ? a : b;
}

// ---------------- K1: fused decode + per-anchor best gt + per-(chunk,g) best anchor -----
// grid 64 rows * 64 chunks. Writes ws_ov/ws_idx (per-anchor) and ws_part (per chunk,g).
__global__ __launch_bounds__(256) void k_match(
    const float* __restrict__ anchors,     // [NA*4] cxcywh
    const float* __restrict__ refine_loc,  // [NB*NA*4]
    const float* __restrict__ gt_boxes,    // [NB*NG*4] xyxy
    float* __restrict__ ws_ov,             // [2*NB*NA]
    unsigned char* __restrict__ ws_idx,    // [2*NB*NA]
    unsigned long long* __restrict__ ws_part) // [64*64*NG] plain stores
{
    int row = blockIdx.x >> 6;             // 0..63 = lossId*32 + b
    int chunk = blockIdx.x & 63;
    int lossId = row >> 5, b = row & 31;
    int tid = threadIdx.x;
    __shared__ float4 s_gt[NG];
    __shared__ float s_ga[NG];
    __shared__ unsigned long long s_part[4][NG];
    if (tid < NG) {
        float4 g = *(const float4*)&gt_boxes[(size_t)(b * NG + tid) * 4];
        s_gt[tid] = g;
        s_ga[tid] = (g.z - g.x) * (g.w - g.y);
    }
    __syncthreads();
    int a = chunk * 256 + tid;
    bool valid = a < NA;
    int al = valid ? a : NA - 1;
    float4 an = *(const float4*)&anchors[(size_t)al * 4];
    float acx = an.x, acy = an.y, aw = an.z, ah = an.w;
    if (lossId) {
        float4 rl = *(const float4*)&refine_loc[((size_t)b * NA + al) * 4];
        acx += rl.x * 0.1f * aw;
        acy += rl.y * 0.1f * ah;
        aw *= __expf(rl.z * 0.2f);
        ah *= __expf(rl.w * 0.2f);
    }
    float ax1 = acx - aw * 0.5f, ay1 = acy - ah * 0.5f;
    float ax2 = acx + aw * 0.5f, ay2 = acy + ah * 0.5f;
    float aarea = (ax2 - ax1) * (ay2 - ay1);

    float ovg[NG];
    float best = -1.f; int bg = 0;
    #pragma unroll
    for (int g = 0; g < NG; g++) {
        float4 G = s_gt[g];
        float tlx = fmaxf(G.x, ax1);
        float tly = fmaxf(G.y, ay1);
        float brx = fminf(G.z, ax2);
        float bry = fminf(G.w, ay2);
        float w = brx - tlx; w = w > 0.f ? w : 0.f;
        float h = bry - tly; h = h > 0.f ? h : 0.f;
        float inter = w * h;
        float uni = s_ga[g] + aarea - inter;
        float ov = inter * __builtin_amdgcn_rcpf(uni);
        if (!valid) ov = 0.f;              // neutral: loses all key comparisons to real a
        ovg[g] = ov;
        if (ov > best) { best = ov; bg = g; }   // strict > keeps first (smallest) g
    }
    if (valid) {
        size_t sec = (size_t)row * NA;
        ws_ov[sec + a] = best;
        ws_idx[sec + a] = (unsigned char)bg;
    }
    // per-g wave-level argmax (smallest a on ties via ballot-first; lanes are ascending a)
    int lane = tid & 63, wv = tid >> 6;
    #pragma unroll
    for (int g = 0; g < NG; g++) {
        float m = ovg[g];
        m = fmaxf(m, __shfl_xor(m, 1));
        m = fmaxf(m, __shfl_xor(m, 2));
        m = fmaxf(m, __shfl_xor(m, 4));
        m = fmaxf(m, __shfl_xor(m, 8));
        m = fmaxf(m, __shfl_xor(m, 16));
        m = fmaxf(m, __shfl_xor(m, 32));
        unsigned long long ball = __ballot(ovg[g] == m);
        int first = __ffsll((long long)ball) - 1;
        if (lane == 0) {
            unsigned aw_ = (unsigned)(chunk * 256 + wv * 64 + first);
            s_part[wv][g] = ((unsigned long long)__float_as_uint(m) << 32)
                            | (0xFFFFFFFFu - aw_);
        }
    }
    __syncthreads();
    if (tid < NG) {
        unsigned long long k = s_part[0][tid];
        #pragma unroll
        for (int i = 1; i < 4; i++) k = umax64(k, s_part[i][tid]);
        ws_part[(size_t)blockIdx.x * NG + tid] = k;
    }
}

// ---------------- K2: part-reduce + override + conf; ARM rows: inline C=2 loss ----------
__global__ __launch_bounds__(256) void k_conf(
    const int* __restrict__ gt_labels,     // [NB*NG]
    const unsigned long long* __restrict__ ws_part,
    const float* __restrict__ ws_ov,
    const unsigned char* __restrict__ ws_idx,
    const float* __restrict__ objectness,  // [NB*NA*2]
    const float* __restrict__ anchors,     // [NA*4]
    const float* __restrict__ gt_boxes,    // [NB*NG*4]
    const float* __restrict__ arm_pred,    // refine_loc: ARM's pred_loc [NB*NA*4]
    int* __restrict__ match,               // [2*NB*NA]; only ODM rows written
    float* __restrict__ negce,             // [2*NB*NA]; ARM section written here
    int* __restrict__ pos_cnt,             // [64*8]
    float2* __restrict__ pConf)            // [64*8] ARM (ce,loc) partials
{
    int row = blockIdx.x >> 3;             // 64 rows
    int chunk = blockIdx.x & 7;            // 8 chunks of 2040
    int lossId = row >> 5, b = row & 31;
    int tid = threadIdx.x;
    __shared__ int s_oa[NG];
    __shared__ int s_lab[NG];
    __shared__ float4 s_gt[NG];
    __shared__ unsigned s_mask[512];       // NA bits
    __shared__ unsigned long long s_pp[8][NG];
    for (int i = tid; i < 512; i += 256) s_mask[i] = 0u;
    {   // reduce 64 chunk-parts per g
        int g = tid & 31, s = tid >> 5;
        unsigned long long k = 0ull;
        for (int c = s; c < 64; c += 8)
            k = umax64(k, ws_part[(size_t)(row * 64 + c) * NG + g]);
        s_pp[s][g] = k;
    }
    __syncthreads();
    if (tid < NG) {
        unsigned long long k = s_pp[0][tid];
        #pragma unroll
        for (int i = 1; i < 8; i++) k = umax64(k, s_pp[i][tid]);
        unsigned a = 0xFFFFFFFFu - (unsigned)(k & 0xFFFFFFFFull);
        s_oa[tid] = (int)a;
        s_lab[tid] = lossId ? gt_labels[b * NG + tid] : 0;
        s_gt[tid] = *(const float4*)&gt_boxes[(size_t)(b * NG + tid) * 4];
        atomicOr(&s_mask[a >> 5], 1u << (a & 31));
    }
    __syncthreads();
    size_t sec = (size_t)row * NA;
    int base = chunk * 2040;
    int cnt = 0;
    float pce = 0.f, ploc = 0.f;
    for (int a = base + tid; a < base + 2040; a += 256) {
        float ov = ws_ov[sec + a];
        int g = ws_idx[sec + a];
        if (s_mask[a >> 5] & (1u << (a & 31))) {
            for (int j = NG - 1; j >= 0; j--)      // last gt wins on duplicates
                if (s_oa[j] == a) { g = j; ov = 2.0f; break; }
        }
        int conf = (ov < 0.5f) ? 0 : (s_lab[g] + 1);
        cnt += (conf > 0);
        if (lossId) {
            match[sec + a] = conf | (g << 16);
        } else {
            // ARM loss inline (C=2)
            size_t idx = sec + a;
            float2 x = *(const float2*)&objectness[idx * 2];
            float mx = fmaxf(x.x, x.y);
            float lse = mx + __logf(__expf(x.x - mx) + __expf(x.y - mx));
            float ce = lse - (conf ? x.y : x.x);
            if (conf > 0) {
                pce += ce;
                negce[idx] = 0.f;
                float4 an = *(const float4*)&anchors[(size_t)a * 4];
                float4 G = s_gt[g];
                float mcx = (G.x + G.z) * 0.5f, mcy = (G.y + G.w) * 0.5f;
                float mw = G.z - G.x, mh = G.w - G.y;
                float t0 = (mcx - an.x) / (0.1f * an.z);
                float t1 = (mcy - an.y) / (0.1f * an.w);
                float t2 = __logf(mw / an.z) / 0.2f;
                float t3 = __logf(mh / an.w) / 0.2f;
                float4 pl = *(const float4*)&arm_pred[idx * 4];
                ploc += sl1(pl.x - t0) + sl1(pl.y - t1) + sl1(pl.z - t2) + sl1(pl.w - t3);
            } else {
                negce[idx] = ce;
            }
        }
    }
    // reduce cnt + (pce,ploc)
    #pragma unroll
    for (int o = 32; o > 0; o >>= 1) {
        cnt += __shfl_down(cnt, o);
        pce += __shfl_down(pce, o);
        ploc += __shfl_down(ploc, o);
    }
    __shared__ int s_c[4];
    __shared__ float s_p0[4], s_p1[4];
    if ((tid & 63) == 0) {
        int w = tid >> 6;
        s_c[w] = cnt; s_p0[w] = pce; s_p1[w] = ploc;
    }
    __syncthreads();
    if (tid == 0) {
        pos_cnt[blockIdx.x] = s_c[0] + s_c[1] + s_c[2] + s_c[3];
        pConf[blockIdx.x] = make_float2(s_p0[0] + s_p0[1] + s_p0[2] + s_p0[3],
                                        s_p1[0] + s_p1[1] + s_p1[2] + s_p1[3]);
    }
}

// block-level (ce,loc) reduction; result valid on tid 0; NO global atomics
__device__ __forceinline__ void block_reduce2_store(float v0, float v1, float2* dst) {
    #pragma unroll
    for (int o = 32; o > 0; o >>= 1) { v0 += __shfl_down(v0, o); v1 += __shfl_down(v1, o); }
    __shared__ float s0[4], s1[4];
    int w = threadIdx.x >> 6;
    if ((threadIdx.x & 63) == 0) { s0[w] = v0; s1[w] = v1; }
    __syncthreads();
    if (threadIdx.x == 0) {
        float t0 = 0.f, t1 = 0.f;
        #pragma unroll
        for (int i = 0; i < 4; i++) { t0 += s0[i]; t1 += s1[i]; }
        *dst = make_float2(t0, t1);
    }
}

// ---------------- K3 helper: one anchor's softmax-CE + loc (8-lane group) ---------------
__device__ __forceinline__ void odm_anchor(
    int idx, const float* x, float x80, int m, int sub,
    const float* __restrict__ anchors, const float* __restrict__ refine_loc,
    const float* __restrict__ gt_boxes, const float* __restrict__ pred_loc,
    float* __restrict__ negce, float& pce, float& ploc)
{
    int conf = m & 0xFFFF; int g = m >> 16;
    float mx = x80;
    #pragma unroll
    for (int j = 0; j < 10; j++) mx = fmaxf(mx, x[j]);
    mx = fmaxf(mx, __shfl_xor(mx, 1));
    mx = fmaxf(mx, __shfl_xor(mx, 2));
    mx = fmaxf(mx, __shfl_xor(mx, 4));
    float s = (sub == 0) ? __expf(x80 - mx) : 0.f;
    float sel = (sub == 0 && conf == 80) ? x80 : 0.f;
    #pragma unroll
    for (int j = 0; j < 10; j++) {
        s += __expf(x[j] - mx);
        sel += (sub + 8 * j == conf) ? x[j] : 0.f;
    }
    s += __shfl_xor(s, 1);   sel += __shfl_xor(sel, 1);
    s += __shfl_xor(s, 2);   sel += __shfl_xor(sel, 2);
    s += __shfl_xor(s, 4);   sel += __shfl_xor(sel, 4);
    float ce = mx + __logf(s) - sel;
    if (sub == 0) {
        if (conf > 0) {
            pce += ce;
            negce[idx] = 0.f;
            int b = idx / NA, a = idx - b * NA;
            float4 an = *(const float4*)&anchors[(size_t)a * 4];
            float4 rl = *(const float4*)&refine_loc[(size_t)idx * 4];
            float acx = an.x + rl.x * 0.1f * an.z;
            float acy = an.y + rl.y * 0.1f * an.w;
            float aw = an.z * __expf(rl.z * 0.2f);
            float ah = an.w * __expf(rl.w * 0.2f);
            const float* gb = &gt_boxes[(size_t)(b * NG + g) * 4];
            float mcx = (gb[0] + gb[2]) * 0.5f, mcy = (gb[1] + gb[3]) * 0.5f;
            float mw = gb[2] - gb[0], mh = gb[3] - gb[1];
            float t0 = (mcx - acx) / (0.1f * aw);
            float t1 = (mcy - acy) / (0.1f * ah);
            float t2 = __logf(mw / aw) / 0.2f;
            float t3 = __logf(mh / ah) / 0.2f;
            float4 pl = *(const float4*)&pred_loc[(size_t)idx * 4];
            ploc += sl1(pl.x - t0) + sl1(pl.y - t1) + sl1(pl.z - t2) + sl1(pl.w - t3);
        } else {
            negce[idx] = ce;
        }
    }
}

// ---------------- K3: ODM loss — grid-stride + 1-deep register prefetch -----------------
__global__ __launch_bounds__(256, 4) void k_odm_loss(
    const float* __restrict__ pred_conf,   // [NB*NA*81]
    const float* __restrict__ pred_loc,
    const float* __restrict__ anchors,
    const float* __restrict__ refine_loc,
    const float* __restrict__ gt_boxes,
    const int* __restrict__ match,         // ODM section
    float* __restrict__ negce,             // ODM section
    float2* __restrict__ partial)          // [ODM_GRID]
{
    int lane = threadIdx.x & 63;
    int sub = lane & 7;
    int grp = lane >> 3;
    int wid = blockIdx.x * 4 + (threadIdx.x >> 6);
    const int NWAVE = ODM_GRID * 4;
    const int TOT = NB * NA / 8;           // 65280 groups of 8 anchors
    float pce = 0.f, ploc = 0.f;

    float x[10], x80; int m, idx;
    {   // prologue load
        idx = wid * 8 + grp;
        const float* p = pred_conf + (size_t)idx * NC;
        #pragma unroll
        for (int j = 0; j < 10; j++) x[j] = p[sub + 8 * j];
        x80 = (sub == 0) ? p[80] : -3.0e38f;
        m = match[idx];
    }
    for (int gi = wid; gi < TOT; gi += NWAVE) {
        float y[10], y80 = 0.f; int my = 0, idxy = 0;
        int nx = gi + NWAVE;
        if (nx < TOT) {                    // prefetch next tile while computing current
            idxy = nx * 8 + grp;
            const float* p = pred_conf + (size_t)idxy * NC;
            #pragma unroll
            for (int j = 0; j < 10; j++) y[j] = p[sub + 8 * j];
            y80 = (sub == 0) ? p[80] : -3.0e38f;
            my = match[idxy];
        }
        odm_anchor(idx, x, x80, m, sub, anchors, refine_loc, gt_boxes, pred_loc,
                   negce, pce, ploc);
        #pragma unroll
        for (int j = 0; j < 10; j++) x[j] = y[j];
        x80 = y80; m = my; idx = idxy;
    }
    block_reduce2_store(pce, ploc, &partial[blockIdx.x]);
}

// ---------------- K4: per-image hard-negative top-k sum (register-resident) -------------
__global__ __launch_bounds__(256) void k_topk(
    const float* __restrict__ negce,   // [2*NB*NA], positives marked 0.0
    const int* __restrict__ pos_cnt,   // [64*8]
    float* __restrict__ topk)          // [2*NB]
{
    int blk = blockIdx.x;              // 2*NB
    int tid = threadIdx.x;
    size_t sec = (size_t)blk * NA;
    float v[64];
    #pragma unroll
    for (int q = 0; q < 64; q++) {
        int i = tid + (q << 8);
        v[q] = (i < NA) ? negce[sec + i] : 0.f;
    }
    __shared__ int s_red[4];
    __shared__ float s_redf[4];
    int p = 0;
    #pragma unroll
    for (int j = 0; j < 8; j++) p += pos_cnt[blk * 8 + j];
    int k = p * 3; if (k > NA - p) k = NA - p; if (k < 10) k = 10;

    unsigned lo = 0u, hi = 0x7F800000u;
    while (lo < hi) {
        unsigned mid = (lo + hi) >> 1;
        float fmid = __uint_as_float(mid);
        int c = 0;
        #pragma unroll
        for (int q = 0; q < 64; q++) c += (v[q] > fmid);
        #pragma unroll
        for (int o = 32; o > 0; o >>= 1) c += __shfl_down(c, o);
        if ((tid & 63) == 0) s_red[tid >> 6] = c;
        __syncthreads();
        int total = s_red[0] + s_red[1] + s_red[2] + s_red[3];
        __syncthreads();
        if (total < k) hi = mid; else lo = mid + 1;
    }
    float V = __uint_as_float(lo);
    int c = 0; float sum = 0.f;
    #pragma unroll
    for (int q = 0; q < 64; q++) {
        if (v[q] > V) { c++; sum += v[q]; }
    }
    #pragma unroll
    for (int o = 32; o > 0; o >>= 1) { c += __shfl_down(c, o); sum += __shfl_down(sum, o); }
    if ((tid & 63) == 0) { s_red[tid >> 6] = c; s_redf[tid >> 6] = sum; }
    __syncthreads();
    if (tid == 0) {
        int cg = s_red[0] + s_red[1] + s_red[2] + s_red[3];
        float sg = s_redf[0] + s_redf[1] + s_redf[2] + s_redf[3];
        topk[blk] = sg + (float)(k - cg) * V;
    }
}

// ---------------- K5: final reduce of partials + outputs --------------------------------
__global__ __launch_bounds__(256) void k_final(
    const float2* __restrict__ pConf, const float2* __restrict__ pOdm,
    const int* __restrict__ pos_cnt, const float* __restrict__ topk,
    float* __restrict__ out)
{
    int tid = threadIdx.x;
    float a0 = 0.f, a1 = 0.f, o0 = 0.f, o1 = 0.f;
    for (int i = tid; i < 512; i += 256) { float2 v = pConf[i]; a0 += v.x; a1 += v.y; }
    for (int i = tid; i < ODM_GRID; i += 256) { float2 v = pOdm[i]; o0 += v.x; o1 += v.y; }
    // pos_cnt: entries 0..255 = ARM rows, 256..511 = ODM rows
    float n0 = (float)pos_cnt[tid];
    float n1 = (float)pos_cnt[256 + tid];
    float t0 = (tid < NB) ? topk[tid] : 0.f;
    float t1 = (tid < NB) ? topk[NB + tid] : 0.f;
    #pragma unroll
    for (int o = 32; o > 0; o >>= 1) {
        a0 += __shfl_down(a0, o); a1 += __shfl_down(a1, o);
        o0 += __shfl_down(o0, o); o1 += __shfl_down(o1, o);
        n0 += __shfl_down(n0, o); n1 += __shfl_down(n1, o);
        t0 += __shfl_down(t0, o); t1 += __shfl_down(t1, o);
    }
    __shared__ float s[4][8];
    if ((tid & 63) == 0) {
        int w = tid >> 6;
        s[w][0] = a0; s[w][1] = a1; s[w][2] = o0; s[w][3] = o1;
        s[w][4] = n0; s[w][5] = n1; s[w][6] = t0; s[w][7] = t1;
    }
    __syncthreads();
    if (tid == 0) {
        float armce = 0.f, armloc = 0.f, odmce = 0.f, odmloc = 0.f;
        float N0 = 0.f, N1 = 0.f, tk0 = 0.f, tk1 = 0.f;
        #pragma unroll
        for (int i = 0; i < 4; i++) {
            armce += s[i][0]; armloc += s[i][1]; odmce += s[i][2]; odmloc += s[i][3];
            N0 += s[i][4]; N1 += s[i][5]; tk0 += s[i][6]; tk1 += s[i][7];
        }
        float cls0 = (armce + tk0) / N0, loc0 = armloc / N0;
        float cls1 = (odmce + tk1) / N1, loc1 = odmloc / N1;
        out[0] = cls0 + loc0 + cls1 + loc1;
        out[1] = cls1;
        out[2] = loc1;
        out[3] = cls0;
        out[4] = loc0;
    }
}

extern "C" void kernel_launch(void* const* d_in, const int* in_sizes, int n_in,
                              void* d_out, int out_size, void* d_ws, size_t ws_size,
                              hipStream_t stream) {
    const float* objectness = (const float*)d_in[0];
    const float* refine_loc = (const float*)d_in[1];
    const float* pred_conf  = (const float*)d_in[2];
    const float* pred_loc   = (const float*)d_in[3];
    const float* anchors    = (const float*)d_in[4];  // [1,NA,4] -> a0
    const float* gt_boxes   = (const float*)d_in[5];
    const int*   gt_labels  = (const int*)d_in[6];

    char* w = (char*)d_ws;
    size_t off = 0;
    int* pos_cnt = (int*)(w + off); off += 512 * sizeof(int);          // fully written by k_conf
    float* topk = (float*)(w + off); off += 64 * sizeof(float);
    off = (off + 15) & ~(size_t)15;
    float2* pConf = (float2*)(w + off); off += 512 * 8;
    float2* pOdm = (float2*)(w + off); off += (size_t)ODM_GRID * 8;
    unsigned long long* ws_part = (unsigned long long*)(w + off);
    off += (size_t)64 * 64 * NG * 8;                                   // 1 MB, fully written
    off = (off + 15) & ~(size_t)15;
    float* ws_ov = (float*)(w + off); off += (size_t)2 * NB * NA * 4;
    unsigned char* ws_idx = (unsigned char*)(w + off); off += (size_t)2 * NB * NA;
    off = (off + 15) & ~(size_t)15;
    int* match = (int*)(w + off); off += (size_t)2 * NB * NA * 4;
    float* negce = (float*)(w + off); off += (size_t)2 * NB * NA * 4;

    k_match<<<64 * 64, 256, 0, stream>>>(anchors, refine_loc, gt_boxes,
                                         ws_ov, ws_idx, ws_part);
    k_conf<<<64 * 8, 256, 0, stream>>>(gt_labels, ws_part, ws_ov, ws_idx,
                                       objectness, anchors, gt_boxes, refine_loc,
                                       match, negce, pos_cnt, pConf);
    k_odm_loss<<<ODM_GRID, 256, 0, stream>>>(pred_conf, pred_loc, anchors, refine_loc,
                                             gt_boxes, match + (size_t)NB * NA,
                                             negce + (size_t)NB * NA, pOdm);
    k_topk<<<2 * NB, 256, 0, stream>>>(negce, pos_cnt, topk);
    k_final<<<1, 256, 0, stream>>>(pConf, pOdm, pos_cnt, topk, (float*)d_out);
}